// Round 3
// baseline (752.638 us; speedup 1.0000x reference)
//
#include <hip/hip_runtime.h>
#include <hip/hip_bf16.h>

// GCN forward: out = spmm(A, relu(spmm(A, x@W1)+b1) @ W2) + b2
// bf16 intermediate pipeline: GEMM1 + GEMM2 via MFMA bf16, H1/AGG/H2 stored bf16.
// R5: gemm2 rewritten barrier-free over L2-resident W2t (was latency-bound).
// R6: spmm 4/2-deep gather unroll. gemm1 131us latency-bound.
// R7: gemm1 A-dbuf + B-direct: only 131->123us. MfmaUtil still 8%; the
//     global->cvt->LDS->barrier chain itself is the stall, occupancy too low
//     to hide it (avg wave lifetime ~44us vs ~5us work).
// R8: gemm1 rewritten gemm2-style: NO LDS, NO barriers. Lane loads its
//     16x16x32 A-fragment (8 contiguous f32 = 32B) direct from global,
//     converts to bf16 in-register, B-frags direct from L2-resident W1t.
//     4-wave A redundancy absorbed by L1. spmm2 unroll 2->4.

#define NFEATS 512
#define NHIDS  256
#define NCLS   40
#define NCLSP  64   // H2 padded feature stride (one 128B line per row)

typedef unsigned short ushort_t;
typedef unsigned int uint_t;
typedef __attribute__((ext_vector_type(8))) short frag8;   // 8 bf16 = 16 B
typedef __attribute__((ext_vector_type(4))) float floatx4;

__device__ __forceinline__ ushort_t f2b(float f) {
    uint_t u = __float_as_uint(f);
    uint_t r = (u + 0x7fffu + ((u >> 16) & 1u)) >> 16;   // RNE
    return (ushort_t)r;
}
__device__ __forceinline__ float b2f(ushort_t b) {
    return __uint_as_float((uint_t)b << 16);
}

// ---------------- CSR build ----------------

__global__ void hist_kernel(const int* __restrict__ row, int* __restrict__ cnt, int E) {
    int e = blockIdx.x * blockDim.x + threadIdx.x;
    if (e < E) atomicAdd(&cnt[row[e]], 1);
}

// device-wide exclusive scan of cnt[N] -> row_ptr[N+1]; zeroes cnt.
#define PS_T 256
#define PS_C 4
#define PS_CHUNK (PS_T * PS_C)   // 1024 elements per block

__global__ __launch_bounds__(PS_T) void scan_partial_kernel(const int* __restrict__ cnt,
                                                            int* __restrict__ blockSums, int N) {
    __shared__ int sm[PS_T];
    int t = threadIdx.x;
    int base = blockIdx.x * PS_CHUNK + t * PS_C;
    int s = 0;
    if (base + PS_C <= N) {
        int4 v = *(const int4*)(cnt + base);
        s = v.x + v.y + v.z + v.w;
    } else {
        for (int i = 0; i < PS_C; i++) if (base + i < N) s += cnt[base + i];
    }
    sm[t] = s;
    __syncthreads();
    for (int off = PS_T / 2; off > 0; off >>= 1) {
        if (t < off) sm[t] += sm[t + off];
        __syncthreads();
    }
    if (t == 0) blockSums[blockIdx.x] = sm[0];
}

#define SS_T 128   // must be >= number of scan blocks (98)
__global__ __launch_bounds__(SS_T) void scan_sums_kernel(int* __restrict__ blockSums, int B) {
    __shared__ int sm[SS_T];
    int t = threadIdx.x;
    int v = (t < B) ? blockSums[t] : 0;
    sm[t] = v;
    __syncthreads();
    for (int off = 1; off < SS_T; off <<= 1) {
        int x = (t >= off) ? sm[t - off] : 0;
        __syncthreads();
        sm[t] += x;
        __syncthreads();
    }
    if (t < B) blockSums[t] = sm[t] - v;   // exclusive
}

__global__ __launch_bounds__(PS_T) void scan_finalize_kernel(int* __restrict__ cnt,
                                                             const int* __restrict__ blockSums,
                                                             int* __restrict__ row_ptr, int N, int E) {
    __shared__ int sm[PS_T];
    int t = threadIdx.x;
    int base = blockIdx.x * PS_CHUNK + t * PS_C;
    int vals[PS_C];
    int s = 0;
#pragma unroll
    for (int i = 0; i < PS_C; i++) {
        int idx = base + i;
        vals[i] = (idx < N) ? cnt[idx] : 0;
        s += vals[i];
    }
    sm[t] = s;
    __syncthreads();
    for (int off = 1; off < PS_T; off <<= 1) {
        int x = (t >= off) ? sm[t - off] : 0;
        __syncthreads();
        sm[t] += x;
        __syncthreads();
    }
    int run = blockSums[blockIdx.x] + sm[t] - s;   // exclusive prefix for this thread
#pragma unroll
    for (int i = 0; i < PS_C; i++) {
        int idx = base + i;
        if (idx < N) {
            row_ptr[idx] = run;
            run += vals[i];
            cnt[idx] = 0;   // reuse as fill counter in scatter
        }
    }
    if (blockIdx.x == 0 && t == 0) row_ptr[N] = E;
}

__global__ void scatter_kernel(const int* __restrict__ row, const int* __restrict__ col,
                               const float* __restrict__ val, const int* __restrict__ row_ptr,
                               int* __restrict__ fill, int2* __restrict__ cv, int E) {
    int e = blockIdx.x * blockDim.x + threadIdx.x;
    if (e < E) {
        int r = row[e];
        int p = row_ptr[r] + atomicAdd(&fill[r], 1);
        cv[p] = make_int2(col[e], __float_as_int(val[e]));
    }
}

// ---------------- weight conversions ----------------

// W1 [512][256] f32 -> W1t [256][512] bf16 (n-major)
__global__ void convert_w1(const float* __restrict__ W1, ushort_t* __restrict__ W1t) {
    int idx = blockIdx.x * 256 + threadIdx.x;   // 131072 total
    int k = idx >> 8, n = idx & 255;
    W1t[n * 512 + k] = f2b(W1[idx]);
}

// W2 [256][40] f32 -> W2t [64][256] bf16 (n-major, rows 40..63 zero)
__global__ void convert_w2(const float* __restrict__ W2, ushort_t* __restrict__ W2t) {
    int idx = blockIdx.x * 256 + threadIdx.x;   // 16384 total
    int n = idx >> 8, k = idx & 255;
    W2t[idx] = (n < NCLS) ? f2b(W2[k * NCLS + n]) : (ushort_t)0;
}

// ---------------- GEMM1: H1 = bf16(x @ W1)  via MFMA, barrier-free ----------------
// block = 64 rows x 256 cols, 4 waves split N (wave w: n = w*64..w*64+63).
// Lane loads its A fragment (8 contiguous f32, 32B) direct from global and
// converts in-register; B frags direct from L2-resident W1t. No LDS, no barriers.

#define G1_BM 64

__global__ __launch_bounds__(256) void gemm1_kernel(const float* __restrict__ A,
                                                    const ushort_t* __restrict__ Bt,
                                                    ushort_t* __restrict__ H1, int M) {
    int tid  = threadIdx.x;
    int wave = tid >> 6, lane = tid & 63;
    int quad = lane >> 4, ln = lane & 15;
    int m0 = blockIdx.x * G1_BM;

    floatx4 acc[4][4] = {};

    // B fragment base: row (wave*64 + nt*16 + ln), k-offset quad*8
    const ushort_t* bbase = Bt + (size_t)(wave * 64 + ln) * NFEATS + quad * 8;

    // A fragment rows (clamped; garbage rows computed but never stored)
    const float* abase[4];
#pragma unroll
    for (int mt = 0; mt < 4; mt++) {
        int m = m0 + mt * 16 + ln;
        if (m > M - 1) m = M - 1;
        abase[mt] = A + (size_t)m * NFEATS + quad * 8;
    }

#pragma unroll
    for (int t = 0; t < NFEATS / 32; ++t) {   // 16 K-steps of 32
        frag8 af[4], bfr[4];
#pragma unroll
        for (int nt = 0; nt < 4; nt++)
            bfr[nt] = *(const frag8*)(bbase + (size_t)nt * 16 * NFEATS + t * 32);
#pragma unroll
        for (int mt = 0; mt < 4; mt++) {
            float4 lo = *(const float4*)(abase[mt] + t * 32);
            float4 hi = *(const float4*)(abase[mt] + t * 32 + 4);
            frag8 f;
            f[0] = (short)f2b(lo.x); f[1] = (short)f2b(lo.y);
            f[2] = (short)f2b(lo.z); f[3] = (short)f2b(lo.w);
            f[4] = (short)f2b(hi.x); f[5] = (short)f2b(hi.y);
            f[6] = (short)f2b(hi.z); f[7] = (short)f2b(hi.w);
            af[mt] = f;
        }
#pragma unroll
        for (int mt = 0; mt < 4; mt++)
#pragma unroll
            for (int nt = 0; nt < 4; nt++)
                acc[mt][nt] = __builtin_amdgcn_mfma_f32_16x16x32_bf16(af[mt], bfr[nt], acc[mt][nt], 0, 0, 0);
    }

    // C/D layout: col = ln, row = quad*4 + i
#pragma unroll
    for (int mt = 0; mt < 4; mt++) {
#pragma unroll
        for (int i = 0; i < 4; i++) {
            int m = m0 + mt * 16 + quad * 4 + i;
            if (m < M) {
#pragma unroll
                for (int nt = 0; nt < 4; nt++) {
                    H1[(size_t)m * NHIDS + wave * 64 + nt * 16 + ln] = f2b(acc[mt][nt][i]);
                }
            }
        }
    }
}

// ---------------- SpMM1: AGG = bf16(relu(A_hat @ H1 + b1)), F=256 ----------------
// one wave per row; 4-deep gather unroll for memory-level parallelism.

__global__ __launch_bounds__(256) void spmm1_kernel(const int* __restrict__ row_ptr,
                                                    const int2* __restrict__ cv,
                                                    const ushort_t* __restrict__ H1,
                                                    const float* __restrict__ b1,
                                                    ushort_t* __restrict__ AGG, int N) {
    int wave = threadIdx.x >> 6, lane = threadIdx.x & 63;
    int r = blockIdx.x * 4 + wave;
    if (r >= N) return;
    int s = row_ptr[r], e = row_ptr[r + 1];
    float a0 = 0.f, a1 = 0.f, a2 = 0.f, a3 = 0.f;
    int j = s;
    for (; j + 3 < e; j += 4) {
        int2 p0 = cv[j];
        int2 p1 = cv[j + 1];
        int2 p2 = cv[j + 2];
        int2 p3 = cv[j + 3];
        ushort4 h0 = *(const ushort4*)(H1 + (size_t)p0.x * NHIDS + lane * 4);
        ushort4 h1 = *(const ushort4*)(H1 + (size_t)p1.x * NHIDS + lane * 4);
        ushort4 h2 = *(const ushort4*)(H1 + (size_t)p2.x * NHIDS + lane * 4);
        ushort4 h3 = *(const ushort4*)(H1 + (size_t)p3.x * NHIDS + lane * 4);
        float v0 = __int_as_float(p0.y), v1 = __int_as_float(p1.y);
        float v2 = __int_as_float(p2.y), v3 = __int_as_float(p3.y);
        a0 += v0 * b2f(h0.x); a1 += v0 * b2f(h0.y); a2 += v0 * b2f(h0.z); a3 += v0 * b2f(h0.w);
        a0 += v1 * b2f(h1.x); a1 += v1 * b2f(h1.y); a2 += v1 * b2f(h1.z); a3 += v1 * b2f(h1.w);
        a0 += v2 * b2f(h2.x); a1 += v2 * b2f(h2.y); a2 += v2 * b2f(h2.z); a3 += v2 * b2f(h2.w);
        a0 += v3 * b2f(h3.x); a1 += v3 * b2f(h3.y); a2 += v3 * b2f(h3.z); a3 += v3 * b2f(h3.w);
    }
    for (; j < e; j++) {
        int2 p0 = cv[j];
        ushort4 h0 = *(const ushort4*)(H1 + (size_t)p0.x * NHIDS + lane * 4);
        float v0 = __int_as_float(p0.y);
        a0 += v0 * b2f(h0.x); a1 += v0 * b2f(h0.y); a2 += v0 * b2f(h0.z); a3 += v0 * b2f(h0.w);
    }
    float4 bb = *(const float4*)(b1 + lane * 4);
    a0 += bb.x; a1 += bb.y; a2 += bb.z; a3 += bb.w;
    ushort4 o;
    o.x = f2b(a0 > 0.f ? a0 : 0.f);
    o.y = f2b(a1 > 0.f ? a1 : 0.f);
    o.z = f2b(a2 > 0.f ? a2 : 0.f);
    o.w = f2b(a3 > 0.f ? a3 : 0.f);
    *(ushort4*)&AGG[(size_t)r * NHIDS + lane * 4] = o;
}

// ---------------- GEMM2: H2 = bf16(AGG @ W2) via MFMA, padded to 64 cols ----------------
// 256 threads = 4 waves; block covers 256 rows (wave w: rows w*64..w*64+63).
// All 64 output cols per wave = 4 n-tiles; K=256 = 8 chunks of 32. No LDS, no barriers:
// A-frags direct from AGG (16B/lane), B-frags from W2t (32 KB, L1/L2-resident).

__global__ __launch_bounds__(256) void gemm2_kernel(const ushort_t* __restrict__ AGG,
                                                    const ushort_t* __restrict__ W2t,
                                                    ushort_t* __restrict__ H2, int M) {
    int tid  = threadIdx.x;
    int wave = tid >> 6, lane = tid & 63;
    int quad = lane >> 4, ln = lane & 15;
    int m0 = blockIdx.x * 256 + wave * 64;

    floatx4 acc[4][4] = {};
    frag8 zf = {};

#pragma unroll
    for (int k0 = 0; k0 < NHIDS; k0 += 32) {
        frag8 af[4], bf[4];
#pragma unroll
        for (int mt = 0; mt < 4; mt++) {
            int m = m0 + mt * 16 + ln;
            af[mt] = (m < M) ? *(const frag8*)(AGG + (size_t)m * NHIDS + k0 + quad * 8) : zf;
        }
#pragma unroll
        for (int nt = 0; nt < 4; nt++)
            bf[nt] = *(const frag8*)(W2t + (size_t)(nt * 16 + ln) * NHIDS + k0 + quad * 8);
#pragma unroll
        for (int mt = 0; mt < 4; mt++)
#pragma unroll
            for (int nt = 0; nt < 4; nt++)
                acc[mt][nt] = __builtin_amdgcn_mfma_f32_16x16x32_bf16(af[mt], bf[nt], acc[mt][nt], 0, 0, 0);
    }
    // C/D layout: col = ln, row = quad*4 + i
#pragma unroll
    for (int mt = 0; mt < 4; mt++) {
#pragma unroll
        for (int i = 0; i < 4; i++) {
            int m = m0 + mt * 16 + quad * 4 + i;
            if (m < M) {
#pragma unroll
                for (int nt = 0; nt < 4; nt++)
                    H2[(size_t)m * NCLSP + nt * 16 + ln] = f2b(acc[mt][nt][i]);
            }
        }
    }
}

// ---------------- SpMM2: out = A_hat @ H2 + b2, F=40 (padded reads of 64) ----------------
// 4-deep gather unroll.

__global__ __launch_bounds__(256) void spmm2_kernel(const int* __restrict__ row_ptr,
                                                    const int2* __restrict__ cv,
                                                    const ushort_t* __restrict__ H2,
                                                    const float* __restrict__ b2,
                                                    float* __restrict__ out, int N) {
    int wave = threadIdx.x >> 6, lane = threadIdx.x & 63;
    int half = lane >> 5, fl = lane & 31;
    int r = blockIdx.x * 8 + wave * 2 + half;
    if (r >= N) return;
    int s = row_ptr[r], e = row_ptr[r + 1];
    float a0 = 0.f, a1 = 0.f;
    int j = s;
    for (; j + 3 < e; j += 4) {
        int2 p0 = cv[j];
        int2 p1 = cv[j + 1];
        int2 p2 = cv[j + 2];
        int2 p3 = cv[j + 3];
        float v0 = __int_as_float(p0.y);
        float v1 = __int_as_float(p1.y);
        float v2 = __int_as_float(p2.y);
        float v3 = __int_as_float(p3.y);
        uint_t h0 = *(const uint_t*)(H2 + (size_t)p0.x * NCLSP + fl * 2);
        uint_t h1 = *(const uint_t*)(H2 + (size_t)p1.x * NCLSP + fl * 2);
        uint_t h2 = *(const uint_t*)(H2 + (size_t)p2.x * NCLSP + fl * 2);
        uint_t h3 = *(const uint_t*)(H2 + (size_t)p3.x * NCLSP + fl * 2);
        a0 += v0 * b2f((ushort_t)(h0 & 0xffff));
        a1 += v0 * b2f((ushort_t)(h0 >> 16));
        a0 += v1 * b2f((ushort_t)(h1 & 0xffff));
        a1 += v1 * b2f((ushort_t)(h1 >> 16));
        a0 += v2 * b2f((ushort_t)(h2 & 0xffff));
        a1 += v2 * b2f((ushort_t)(h2 >> 16));
        a0 += v3 * b2f((ushort_t)(h3 & 0xffff));
        a1 += v3 * b2f((ushort_t)(h3 >> 16));
    }
    for (; j < e; j++) {
        int2 p = cv[j];
        float v = __int_as_float(p.y);
        uint_t h = *(const uint_t*)(H2 + (size_t)p.x * NCLSP + fl * 2);
        a0 += v * b2f((ushort_t)(h & 0xffff));
        a1 += v * b2f((ushort_t)(h >> 16));
    }
    if (fl < NCLS / 2) {
        float2 o;
        o.x = a0 + b2[fl * 2];
        o.y = a1 + b2[fl * 2 + 1];
        *(float2*)(out + (size_t)r * NCLS + fl * 2) = o;
    }
}

// ---------------- launch ----------------

static inline size_t align256(size_t x) { return (x + 255) & ~(size_t)255; }

extern "C" void kernel_launch(void* const* d_in, const int* in_sizes, int n_in,
                              void* d_out, int out_size, void* d_ws, size_t ws_size,
                              hipStream_t stream) {
    const float* x        = (const float*)d_in[0];
    const float* W1       = (const float*)d_in[1];
    const float* b1       = (const float*)d_in[2];
    const float* W2       = (const float*)d_in[3];
    const float* b2       = (const float*)d_in[4];
    const int*   edge_row = (const int*)d_in[5];
    const int*   edge_col = (const int*)d_in[6];
    const float* edge_val = (const float*)d_in[7];
    float* out = (float*)d_out;

    int N = in_sizes[0] / NFEATS;  // 100000
    int E = in_sizes[5];           // 1700000

    char* w = (char*)d_ws;
    size_t off = 0;
    ushort_t* H1   = (ushort_t*)(w + off); off += align256((size_t)N * NHIDS * 2);
    ushort_t* AGG  = (ushort_t*)(w + off); off += align256((size_t)N * NHIDS * 2);
    ushort_t* H2   = (ushort_t*)(w + off); off += align256((size_t)N * NCLSP * 2);
    ushort_t* W1t  = (ushort_t*)(w + off); off += align256((size_t)NHIDS * NFEATS * 2);
    ushort_t* W2t  = (ushort_t*)(w + off); off += align256((size_t)NCLSP * NHIDS * 2);
    int*      row_ptr = (int*)(w + off); off += align256((size_t)(N + 1) * 4);
    int*      cnt     = (int*)(w + off); off += align256((size_t)N * 4);
    int*      blockSums = (int*)(w + off); off += align256((size_t)SS_T * 4);
    int2*     cv      = (int2*)(w + off); off += align256((size_t)E * 8);

    int scanB = (N + PS_CHUNK - 1) / PS_CHUNK;   // 98 for N=100000 (must be <= SS_T)

    // CSR build + weight conversion
    hipMemsetAsync(cnt, 0, (size_t)N * 4, stream);
    hist_kernel<<<(E + 255) / 256, 256, 0, stream>>>(edge_row, cnt, E);
    convert_w1<<<(NFEATS * NHIDS) / 256, 256, 0, stream>>>(W1, W1t);
    convert_w2<<<(NCLSP * NHIDS) / 256, 256, 0, stream>>>(W2, W2t);
    scan_partial_kernel<<<scanB, PS_T, 0, stream>>>(cnt, blockSums, N);
    scan_sums_kernel<<<1, SS_T, 0, stream>>>(blockSums, scanB);
    scan_finalize_kernel<<<scanB, PS_T, 0, stream>>>(cnt, blockSums, row_ptr, N, E);
    scatter_kernel<<<(E + 255) / 256, 256, 0, stream>>>(edge_row, edge_col, edge_val,
                                                        row_ptr, cnt, cv, E);

    // layer 1
    gemm1_kernel<<<(N + G1_BM - 1) / G1_BM, 256, 0, stream>>>(x, W1t, H1, N);
    spmm1_kernel<<<(N + 3) / 4, 256, 0, stream>>>(row_ptr, cv, H1, b1, AGG, N);

    // layer 2
    gemm2_kernel<<<(N + 255) / 256, 256, 0, stream>>>(AGG, W2t, H2, N);
    spmm2_kernel<<<(N + 7) / 8, 256, 0, stream>>>(row_ptr, cv, H2, b2, out, N);
}

// Round 4
// 688.156 us; speedup vs baseline: 1.0937x; 1.0937x over previous
//
#include <hip/hip_runtime.h>
#include <hip/hip_bf16.h>

// GCN forward: out = spmm(A, relu(spmm(A, x@W1)+b1) @ W2) + b2
// bf16 intermediate pipeline: GEMM1 + GEMM2 via MFMA bf16, H1/AGG/H2 stored bf16.
// R6: spmm 4/2-deep gather unroll. gemm1 131us latency-bound.
// R7: gemm1 A-dbuf(VGPR roundtrip) + B-direct: 123us. MfmaUtil 8%.
// R8: barrier-free direct-global A: REGRESSED 195us (scattered 16-row loads,
//     96 cvt VALU/step on critical path). Reverting to staged structure.
// R9: gemm1 stages A as raw f32 via async global_load_lds(16B) (no VGPR
//     roundtrip), dbuf 2x8KB, one barrier/step; XOR-swizzled LDS slots via
//     pre-swizzled global source (guide m173/m201 pattern) to kill the
//     16-way stride-128B read conflict; f32->bf16 via v_cvt_pk_bf16_f32
//     (16 instrs/step) at fragment-read time. B direct from L2-resident W1t.

#define NFEATS 512
#define NHIDS  256
#define NCLS   40
#define NCLSP  64   // H2 padded feature stride (one 128B line per row)

typedef unsigned short ushort_t;
typedef unsigned int uint_t;
typedef __attribute__((ext_vector_type(8))) short frag8;   // 8 bf16 = 16 B
typedef __attribute__((ext_vector_type(4))) float floatx4;

#define AS1C(p) ((__attribute__((address_space(1))) const void*)(p))
#define AS3(p)  ((__attribute__((address_space(3))) void*)(p))

__device__ __forceinline__ ushort_t f2b(float f) {
    uint_t u = __float_as_uint(f);
    uint_t r = (u + 0x7fffu + ((u >> 16) & 1u)) >> 16;   // RNE
    return (ushort_t)r;
}
__device__ __forceinline__ float b2f(ushort_t b) {
    return __uint_as_float((uint_t)b << 16);
}

// ---------------- CSR build ----------------

__global__ void hist_kernel(const int* __restrict__ row, int* __restrict__ cnt, int E) {
    int e = blockIdx.x * blockDim.x + threadIdx.x;
    if (e < E) atomicAdd(&cnt[row[e]], 1);
}

// device-wide exclusive scan of cnt[N] -> row_ptr[N+1]; zeroes cnt.
#define PS_T 256
#define PS_C 4
#define PS_CHUNK (PS_T * PS_C)   // 1024 elements per block

__global__ __launch_bounds__(PS_T) void scan_partial_kernel(const int* __restrict__ cnt,
                                                            int* __restrict__ blockSums, int N) {
    __shared__ int sm[PS_T];
    int t = threadIdx.x;
    int base = blockIdx.x * PS_CHUNK + t * PS_C;
    int s = 0;
    if (base + PS_C <= N) {
        int4 v = *(const int4*)(cnt + base);
        s = v.x + v.y + v.z + v.w;
    } else {
        for (int i = 0; i < PS_C; i++) if (base + i < N) s += cnt[base + i];
    }
    sm[t] = s;
    __syncthreads();
    for (int off = PS_T / 2; off > 0; off >>= 1) {
        if (t < off) sm[t] += sm[t + off];
        __syncthreads();
    }
    if (t == 0) blockSums[blockIdx.x] = sm[0];
}

#define SS_T 128   // must be >= number of scan blocks (98)
__global__ __launch_bounds__(SS_T) void scan_sums_kernel(int* __restrict__ blockSums, int B) {
    __shared__ int sm[SS_T];
    int t = threadIdx.x;
    int v = (t < B) ? blockSums[t] : 0;
    sm[t] = v;
    __syncthreads();
    for (int off = 1; off < SS_T; off <<= 1) {
        int x = (t >= off) ? sm[t - off] : 0;
        __syncthreads();
        sm[t] += x;
        __syncthreads();
    }
    if (t < B) blockSums[t] = sm[t] - v;   // exclusive
}

__global__ __launch_bounds__(PS_T) void scan_finalize_kernel(int* __restrict__ cnt,
                                                             const int* __restrict__ blockSums,
                                                             int* __restrict__ row_ptr, int N, int E) {
    __shared__ int sm[PS_T];
    int t = threadIdx.x;
    int base = blockIdx.x * PS_CHUNK + t * PS_C;
    int vals[PS_C];
    int s = 0;
#pragma unroll
    for (int i = 0; i < PS_C; i++) {
        int idx = base + i;
        vals[i] = (idx < N) ? cnt[idx] : 0;
        s += vals[i];
    }
    sm[t] = s;
    __syncthreads();
    for (int off = 1; off < PS_T; off <<= 1) {
        int x = (t >= off) ? sm[t - off] : 0;
        __syncthreads();
        sm[t] += x;
        __syncthreads();
    }
    int run = blockSums[blockIdx.x] + sm[t] - s;   // exclusive prefix for this thread
#pragma unroll
    for (int i = 0; i < PS_C; i++) {
        int idx = base + i;
        if (idx < N) {
            row_ptr[idx] = run;
            run += vals[i];
            cnt[idx] = 0;   // reuse as fill counter in scatter
        }
    }
    if (blockIdx.x == 0 && t == 0) row_ptr[N] = E;
}

__global__ void scatter_kernel(const int* __restrict__ row, const int* __restrict__ col,
                               const float* __restrict__ val, const int* __restrict__ row_ptr,
                               int* __restrict__ fill, int2* __restrict__ cv, int E) {
    int e = blockIdx.x * blockDim.x + threadIdx.x;
    if (e < E) {
        int r = row[e];
        int p = row_ptr[r] + atomicAdd(&fill[r], 1);
        cv[p] = make_int2(col[e], __float_as_int(val[e]));
    }
}

// ---------------- weight conversions ----------------

// W1 [512][256] f32 -> W1t [256][512] bf16 (n-major)
__global__ void convert_w1(const float* __restrict__ W1, ushort_t* __restrict__ W1t) {
    int idx = blockIdx.x * 256 + threadIdx.x;   // 131072 total
    int k = idx >> 8, n = idx & 255;
    W1t[n * 512 + k] = f2b(W1[idx]);
}

// W2 [256][40] f32 -> W2t [64][256] bf16 (n-major, rows 40..63 zero)
__global__ void convert_w2(const float* __restrict__ W2, ushort_t* __restrict__ W2t) {
    int idx = blockIdx.x * 256 + threadIdx.x;   // 16384 total
    int n = idx >> 8, k = idx & 255;
    W2t[idx] = (n < NCLS) ? f2b(W2[k * NCLS + n]) : (ushort_t)0;
}

// ---------------- GEMM1: H1 = bf16(x @ W1)  via MFMA ----------------
// tile 64(M) x 256(N), BK=32 f32, 4 waves split N (wave w: n = w*64..+63).
// A staged raw-f32 via async global_load_lds(16B), double-buffered 2x8KB,
// one barrier per K-step. LDS slots XOR-swizzled (slot ^= row&7) via
// pre-swizzled GLOBAL source (linear LDS dest required by global_load_lds);
// each 8-lane staging group still covers one aligned 128B row -> coalesced.
// Fragment read: 2x ds_read_b128 (f32) + 4x v_cvt_pk_bf16_f32 per m-tile.
// B fragments direct from L2-resident W1t (256 KB).

#define G1_BM 64
#define G1_BK 32   // f32 per row-chunk = 128 B = 8 slots of 16 B

__global__ __launch_bounds__(256) void gemm1_kernel(const float* __restrict__ A,
                                                    const ushort_t* __restrict__ Bt,
                                                    ushort_t* __restrict__ H1, int M) {
    __shared__ float As[2][G1_BM * G1_BK];   // 2 x 8192 B
    int tid  = threadIdx.x;
    int wave = tid >> 6, lane = tid & 63;
    int quad = lane >> 4, ln = lane & 15;
    int m0 = blockIdx.x * G1_BM;

    // ---- staging geometry: wave w call c covers rows (w*2+c)*8 .. +7 ----
    // lane L: local row = g*8 + (L>>3), dest slot = L&7 (linear),
    // source slot = (L&7) ^ ((L>>3)&7)  [XOR swizzle, row&7 == (L>>3)&7]
    int rloc0 = (wave * 2 + 0) * 8 + (lane >> 3);
    int rloc1 = (wave * 2 + 1) * 8 + (lane >> 3);
    int sslot = (lane & 7) ^ ((lane >> 3) & 7);
    int gr0 = m0 + rloc0; if (gr0 > M - 1) gr0 = M - 1;   // clamp: dup rows, never stored
    int gr1 = m0 + rloc1; if (gr1 > M - 1) gr1 = M - 1;
    const float* src0 = A + (size_t)gr0 * NFEATS + sslot * 4;
    const float* src1 = A + (size_t)gr1 * NFEATS + sslot * 4;
    float* dst0 = &As[0][(wave * 2 + 0) * 256];   // 1024 B per group, wave-uniform
    float* dst1 = &As[0][(wave * 2 + 1) * 256];
    float* dst0b = &As[1][(wave * 2 + 0) * 256];
    float* dst1b = &As[1][(wave * 2 + 1) * 256];

    // B fragment base: row (wave*64 + nt*16 + ln), k-offset quad*8
    const ushort_t* bbase = Bt + (size_t)(wave * 64 + ln) * NFEATS + quad * 8;

    floatx4 acc[4][4] = {};

    // prologue: stage k-step 0 into buffer 0
    __builtin_amdgcn_global_load_lds(AS1C(src0), AS3(dst0), 16, 0, 0);
    __builtin_amdgcn_global_load_lds(AS1C(src1), AS3(dst1), 16, 0, 0);
    __syncthreads();

#pragma unroll 2
    for (int t = 0; t < NFEATS / G1_BK; ++t) {   // 16 K-steps
        int cur = t & 1;
        // issue next k-step's async stage into the other buffer
        if (t < NFEATS / G1_BK - 1) {
            const float* s0 = src0 + (t + 1) * G1_BK;
            const float* s1 = src1 + (t + 1) * G1_BK;
            if (cur == 0) {
                __builtin_amdgcn_global_load_lds(AS1C(s0), AS3(dst0b), 16, 0, 0);
                __builtin_amdgcn_global_load_lds(AS1C(s1), AS3(dst1b), 16, 0, 0);
            } else {
                __builtin_amdgcn_global_load_lds(AS1C(s0), AS3(dst0), 16, 0, 0);
                __builtin_amdgcn_global_load_lds(AS1C(s1), AS3(dst1), 16, 0, 0);
            }
        }
        // B fragments direct from global (L2-resident)
        frag8 bfr[4], af[4];
#pragma unroll
        for (int nt = 0; nt < 4; nt++)
            bfr[nt] = *(const frag8*)(bbase + (size_t)nt * 16 * NFEATS + t * G1_BK);
        // A fragments: swizzled ds_read f32 + packed cvt to bf16
#pragma unroll
        for (int mt = 0; mt < 4; mt++) {
            int R = mt * 16 + ln;
            int sw = R & 7;
            const float* base = &As[cur][R * G1_BK];
            float4 lo = *(const float4*)(base + (((2 * quad)     ^ sw) * 4));
            float4 hi = *(const float4*)(base + (((2 * quad + 1) ^ sw) * 4));
            union { frag8 f; uint_t u[4]; } fu;
            asm volatile("v_cvt_pk_bf16_f32 %0, %1, %2" : "=v"(fu.u[0]) : "v"(lo.x), "v"(lo.y));
            asm volatile("v_cvt_pk_bf16_f32 %0, %1, %2" : "=v"(fu.u[1]) : "v"(lo.z), "v"(lo.w));
            asm volatile("v_cvt_pk_bf16_f32 %0, %1, %2" : "=v"(fu.u[2]) : "v"(hi.x), "v"(hi.y));
            asm volatile("v_cvt_pk_bf16_f32 %0, %1, %2" : "=v"(fu.u[3]) : "v"(hi.z), "v"(hi.w));
            af[mt] = fu.f;
        }
#pragma unroll
        for (int mt = 0; mt < 4; mt++)
#pragma unroll
            for (int nt = 0; nt < 4; nt++)
                acc[mt][nt] = __builtin_amdgcn_mfma_f32_16x16x32_bf16(af[mt], bfr[nt], acc[mt][nt], 0, 0, 0);
        __syncthreads();
    }

    // C/D layout: col = ln, row = quad*4 + i
#pragma unroll
    for (int mt = 0; mt < 4; mt++) {
#pragma unroll
        for (int i = 0; i < 4; i++) {
            int m = m0 + mt * 16 + quad * 4 + i;
            if (m < M) {
#pragma unroll
                for (int nt = 0; nt < 4; nt++) {
                    H1[(size_t)m * NHIDS + wave * 64 + nt * 16 + ln] = f2b(acc[mt][nt][i]);
                }
            }
        }
    }
}

// ---------------- SpMM1: AGG = bf16(relu(A_hat @ H1 + b1)), F=256 ----------------
// one wave per row; 4-deep gather unroll for memory-level parallelism.

__global__ __launch_bounds__(256) void spmm1_kernel(const int* __restrict__ row_ptr,
                                                    const int2* __restrict__ cv,
                                                    const ushort_t* __restrict__ H1,
                                                    const float* __restrict__ b1,
                                                    ushort_t* __restrict__ AGG, int N) {
    int wave = threadIdx.x >> 6, lane = threadIdx.x & 63;
    int r = blockIdx.x * 4 + wave;
    if (r >= N) return;
    int s = row_ptr[r], e = row_ptr[r + 1];
    float a0 = 0.f, a1 = 0.f, a2 = 0.f, a3 = 0.f;
    int j = s;
    for (; j + 3 < e; j += 4) {
        int2 p0 = cv[j];
        int2 p1 = cv[j + 1];
        int2 p2 = cv[j + 2];
        int2 p3 = cv[j + 3];
        ushort4 h0 = *(const ushort4*)(H1 + (size_t)p0.x * NHIDS + lane * 4);
        ushort4 h1 = *(const ushort4*)(H1 + (size_t)p1.x * NHIDS + lane * 4);
        ushort4 h2 = *(const ushort4*)(H1 + (size_t)p2.x * NHIDS + lane * 4);
        ushort4 h3 = *(const ushort4*)(H1 + (size_t)p3.x * NHIDS + lane * 4);
        float v0 = __int_as_float(p0.y), v1 = __int_as_float(p1.y);
        float v2 = __int_as_float(p2.y), v3 = __int_as_float(p3.y);
        a0 += v0 * b2f(h0.x); a1 += v0 * b2f(h0.y); a2 += v0 * b2f(h0.z); a3 += v0 * b2f(h0.w);
        a0 += v1 * b2f(h1.x); a1 += v1 * b2f(h1.y); a2 += v1 * b2f(h1.z); a3 += v1 * b2f(h1.w);
        a0 += v2 * b2f(h2.x); a1 += v2 * b2f(h2.y); a2 += v2 * b2f(h2.z); a3 += v2 * b2f(h2.w);
        a0 += v3 * b2f(h3.x); a1 += v3 * b2f(h3.y); a2 += v3 * b2f(h3.z); a3 += v3 * b2f(h3.w);
    }
    for (; j < e; j++) {
        int2 p0 = cv[j];
        ushort4 h0 = *(const ushort4*)(H1 + (size_t)p0.x * NHIDS + lane * 4);
        float v0 = __int_as_float(p0.y);
        a0 += v0 * b2f(h0.x); a1 += v0 * b2f(h0.y); a2 += v0 * b2f(h0.z); a3 += v0 * b2f(h0.w);
    }
    float4 bb = *(const float4*)(b1 + lane * 4);
    a0 += bb.x; a1 += bb.y; a2 += bb.z; a3 += bb.w;
    ushort4 o;
    o.x = f2b(a0 > 0.f ? a0 : 0.f);
    o.y = f2b(a1 > 0.f ? a1 : 0.f);
    o.z = f2b(a2 > 0.f ? a2 : 0.f);
    o.w = f2b(a3 > 0.f ? a3 : 0.f);
    *(ushort4*)&AGG[(size_t)r * NHIDS + lane * 4] = o;
}

// ---------------- GEMM2: H2 = bf16(AGG @ W2) via MFMA, padded to 64 cols ----------------
// 256 threads = 4 waves; block covers 256 rows (wave w: rows w*64..w*64+63).
// All 64 output cols per wave = 4 n-tiles; K=256 = 8 chunks of 32. No LDS, no barriers:
// A-frags direct from AGG (16B/lane), B-frags from W2t (32 KB, L1/L2-resident).

__global__ __launch_bounds__(256) void gemm2_kernel(const ushort_t* __restrict__ AGG,
                                                    const ushort_t* __restrict__ W2t,
                                                    ushort_t* __restrict__ H2, int M) {
    int tid  = threadIdx.x;
    int wave = tid >> 6, lane = tid & 63;
    int quad = lane >> 4, ln = lane & 15;
    int m0 = blockIdx.x * 256 + wave * 64;

    floatx4 acc[4][4] = {};
    frag8 zf = {};

#pragma unroll
    for (int k0 = 0; k0 < NHIDS; k0 += 32) {
        frag8 af[4], bf[4];
#pragma unroll
        for (int mt = 0; mt < 4; mt++) {
            int m = m0 + mt * 16 + ln;
            af[mt] = (m < M) ? *(const frag8*)(AGG + (size_t)m * NHIDS + k0 + quad * 8) : zf;
        }
#pragma unroll
        for (int nt = 0; nt < 4; nt++)
            bf[nt] = *(const frag8*)(W2t + (size_t)(nt * 16 + ln) * NHIDS + k0 + quad * 8);
#pragma unroll
        for (int mt = 0; mt < 4; mt++)
#pragma unroll
            for (int nt = 0; nt < 4; nt++)
                acc[mt][nt] = __builtin_amdgcn_mfma_f32_16x16x32_bf16(af[mt], bf[nt], acc[mt][nt], 0, 0, 0);
    }
    // C/D layout: col = ln, row = quad*4 + i
#pragma unroll
    for (int mt = 0; mt < 4; mt++) {
#pragma unroll
        for (int i = 0; i < 4; i++) {
            int m = m0 + mt * 16 + quad * 4 + i;
            if (m < M) {
#pragma unroll
                for (int nt = 0; nt < 4; nt++)
                    H2[(size_t)m * NCLSP + nt * 16 + ln] = f2b(acc[mt][nt][i]);
            }
        }
    }
}

// ---------------- SpMM2: out = A_hat @ H2 + b2, F=40 (padded reads of 64) ----------------
// 4-deep gather unroll.

__global__ __launch_bounds__(256) void spmm2_kernel(const int* __restrict__ row_ptr,
                                                    const int2* __restrict__ cv,
                                                    const ushort_t* __restrict__ H2,
                                                    const float* __restrict__ b2,
                                                    float* __restrict__ out, int N) {
    int wave = threadIdx.x >> 6, lane = threadIdx.x & 63;
    int half = lane >> 5, fl = lane & 31;
    int r = blockIdx.x * 8 + wave * 2 + half;
    if (r >= N) return;
    int s = row_ptr[r], e = row_ptr[r + 1];
    float a0 = 0.f, a1 = 0.f;
    int j = s;
    for (; j + 3 < e; j += 4) {
        int2 p0 = cv[j];
        int2 p1 = cv[j + 1];
        int2 p2 = cv[j + 2];
        int2 p3 = cv[j + 3];
        float v0 = __int_as_float(p0.y);
        float v1 = __int_as_float(p1.y);
        float v2 = __int_as_float(p2.y);
        float v3 = __int_as_float(p3.y);
        uint_t h0 = *(const uint_t*)(H2 + (size_t)p0.x * NCLSP + fl * 2);
        uint_t h1 = *(const uint_t*)(H2 + (size_t)p1.x * NCLSP + fl * 2);
        uint_t h2 = *(const uint_t*)(H2 + (size_t)p2.x * NCLSP + fl * 2);
        uint_t h3 = *(const uint_t*)(H2 + (size_t)p3.x * NCLSP + fl * 2);
        a0 += v0 * b2f((ushort_t)(h0 & 0xffff));
        a1 += v0 * b2f((ushort_t)(h0 >> 16));
        a0 += v1 * b2f((ushort_t)(h1 & 0xffff));
        a1 += v1 * b2f((ushort_t)(h1 >> 16));
        a0 += v2 * b2f((ushort_t)(h2 & 0xffff));
        a1 += v2 * b2f((ushort_t)(h2 >> 16));
        a0 += v3 * b2f((ushort_t)(h3 & 0xffff));
        a1 += v3 * b2f((ushort_t)(h3 >> 16));
    }
    for (; j < e; j++) {
        int2 p = cv[j];
        float v = __int_as_float(p.y);
        uint_t h = *(const uint_t*)(H2 + (size_t)p.x * NCLSP + fl * 2);
        a0 += v * b2f((ushort_t)(h & 0xffff));
        a1 += v * b2f((ushort_t)(h >> 16));
    }
    if (fl < NCLS / 2) {
        float2 o;
        o.x = a0 + b2[fl * 2];
        o.y = a1 + b2[fl * 2 + 1];
        *(float2*)(out + (size_t)r * NCLS + fl * 2) = o;
    }
}

// ---------------- launch ----------------

static inline size_t align256(size_t x) { return (x + 255) & ~(size_t)255; }

extern "C" void kernel_launch(void* const* d_in, const int* in_sizes, int n_in,
                              void* d_out, int out_size, void* d_ws, size_t ws_size,
                              hipStream_t stream) {
    const float* x        = (const float*)d_in[0];
    const float* W1       = (const float*)d_in[1];
    const float* b1       = (const float*)d_in[2];
    const float* W2       = (const float*)d_in[3];
    const float* b2       = (const float*)d_in[4];
    const int*   edge_row = (const int*)d_in[5];
    const int*   edge_col = (const int*)d_in[6];
    const float* edge_val = (const float*)d_in[7];
    float* out = (float*)d_out;

    int N = in_sizes[0] / NFEATS;  // 100000
    int E = in_sizes[5];           // 1700000

    char* w = (char*)d_ws;
    size_t off = 0;
    ushort_t* H1   = (ushort_t*)(w + off); off += align256((size_t)N * NHIDS * 2);
    ushort_t* AGG  = (ushort_t*)(w + off); off += align256((size_t)N * NHIDS * 2);
    ushort_t* H2   = (ushort_t*)(w + off); off += align256((size_t)N * NCLSP * 2);
    ushort_t* W1t  = (ushort_t*)(w + off); off += align256((size_t)NHIDS * NFEATS * 2);
    ushort_t* W2t  = (ushort_t*)(w + off); off += align256((size_t)NCLSP * NHIDS * 2);
    int*      row_ptr = (int*)(w + off); off += align256((size_t)(N + 1) * 4);
    int*      cnt     = (int*)(w + off); off += align256((size_t)N * 4);
    int*      blockSums = (int*)(w + off); off += align256((size_t)SS_T * 4);
    int2*     cv      = (int2*)(w + off); off += align256((size_t)E * 8);

    int scanB = (N + PS_CHUNK - 1) / PS_CHUNK;   // 98 for N=100000 (must be <= SS_T)

    // CSR build + weight conversion
    hipMemsetAsync(cnt, 0, (size_t)N * 4, stream);
    hist_kernel<<<(E + 255) / 256, 256, 0, stream>>>(edge_row, cnt, E);
    convert_w1<<<(NFEATS * NHIDS) / 256, 256, 0, stream>>>(W1, W1t);
    convert_w2<<<(NCLSP * NHIDS) / 256, 256, 0, stream>>>(W2, W2t);
    scan_partial_kernel<<<scanB, PS_T, 0, stream>>>(cnt, blockSums, N);
    scan_sums_kernel<<<1, SS_T, 0, stream>>>(blockSums, scanB);
    scan_finalize_kernel<<<scanB, PS_T, 0, stream>>>(cnt, blockSums, row_ptr, N, E);
    scatter_kernel<<<(E + 255) / 256, 256, 0, stream>>>(edge_row, edge_col, edge_val,
                                                        row_ptr, cnt, cv, E);

    // layer 1
    gemm1_kernel<<<(N + G1_BM - 1) / G1_BM, 256, 0, stream>>>(x, W1t, H1, N);
    spmm1_kernel<<<(N + 3) / 4, 256, 0, stream>>>(row_ptr, cv, H1, b1, AGG, N);

    // layer 2
    gemm2_kernel<<<(N + 255) / 256, 256, 0, stream>>>(AGG, W2t, H2, N);
    spmm2_kernel<<<(N + 7) / 8, 256, 0, stream>>>(row_ptr, cv, H2, b2, out, N);
}

// Round 5
// 670.962 us; speedup vs baseline: 1.1217x; 1.0256x over previous
//
#include <hip/hip_runtime.h>
#include <hip/hip_bf16.h>

// GCN forward: out = spmm(A, relu(spmm(A, x@W1)+b1) @ W2) + b2
// bf16 intermediate pipeline: GEMM1 + GEMM2 via MFMA bf16, H1/AGG/H2 stored bf16.
// R7: gemm1 A-dbuf + B-direct: 123us. R8: direct-global A: 195us (scattered).
// R9: async global_load_lds A staging + swizzle: 128us. All variants ~125us,
//     all pipes <15% busy => common cost: B-frag loads splinter into 64
//     distinct 16B segments/instr (16 rows x 1KB apart). 400MB of B traffic
//     in 16B segments ~ 25M TA transactions = the latency floor.
// R10: W1/W2 repacked into MFMA-FRAGMENT ORDER (W1f/W2f): each wave B-load
//     is one contiguous 1KB global_load_dwordx4 (1-2 segments, L2-resident).
//     A-path unchanged from R9 (async gload_lds dbuf + XOR swizzle + cvt_pk).

#define NFEATS 512
#define NHIDS  256
#define NCLS   40
#define NCLSP  64   // H2 padded feature stride (one 128B line per row)

typedef unsigned short ushort_t;
typedef unsigned int uint_t;
typedef __attribute__((ext_vector_type(8))) short frag8;   // 8 bf16 = 16 B
typedef __attribute__((ext_vector_type(4))) float floatx4;

#define AS1C(p) ((__attribute__((address_space(1))) const void*)(p))
#define AS3(p)  ((__attribute__((address_space(3))) void*)(p))

__device__ __forceinline__ ushort_t f2b(float f) {
    uint_t u = __float_as_uint(f);
    uint_t r = (u + 0x7fffu + ((u >> 16) & 1u)) >> 16;   // RNE
    return (ushort_t)r;
}
__device__ __forceinline__ float b2f(ushort_t b) {
    return __uint_as_float((uint_t)b << 16);
}

// ---------------- CSR build ----------------

__global__ void hist_kernel(const int* __restrict__ row, int* __restrict__ cnt, int E) {
    int e = blockIdx.x * blockDim.x + threadIdx.x;
    if (e < E) atomicAdd(&cnt[row[e]], 1);
}

// device-wide exclusive scan of cnt[N] -> row_ptr[N+1]; zeroes cnt.
#define PS_T 256
#define PS_C 4
#define PS_CHUNK (PS_T * PS_C)   // 1024 elements per block

__global__ __launch_bounds__(PS_T) void scan_partial_kernel(const int* __restrict__ cnt,
                                                            int* __restrict__ blockSums, int N) {
    __shared__ int sm[PS_T];
    int t = threadIdx.x;
    int base = blockIdx.x * PS_CHUNK + t * PS_C;
    int s = 0;
    if (base + PS_C <= N) {
        int4 v = *(const int4*)(cnt + base);
        s = v.x + v.y + v.z + v.w;
    } else {
        for (int i = 0; i < PS_C; i++) if (base + i < N) s += cnt[base + i];
    }
    sm[t] = s;
    __syncthreads();
    for (int off = PS_T / 2; off > 0; off >>= 1) {
        if (t < off) sm[t] += sm[t + off];
        __syncthreads();
    }
    if (t == 0) blockSums[blockIdx.x] = sm[0];
}

#define SS_T 128   // must be >= number of scan blocks (98)
__global__ __launch_bounds__(SS_T) void scan_sums_kernel(int* __restrict__ blockSums, int B) {
    __shared__ int sm[SS_T];
    int t = threadIdx.x;
    int v = (t < B) ? blockSums[t] : 0;
    sm[t] = v;
    __syncthreads();
    for (int off = 1; off < SS_T; off <<= 1) {
        int x = (t >= off) ? sm[t - off] : 0;
        __syncthreads();
        sm[t] += x;
        __syncthreads();
    }
    if (t < B) blockSums[t] = sm[t] - v;   // exclusive
}

__global__ __launch_bounds__(PS_T) void scan_finalize_kernel(int* __restrict__ cnt,
                                                             const int* __restrict__ blockSums,
                                                             int* __restrict__ row_ptr, int N, int E) {
    __shared__ int sm[PS_T];
    int t = threadIdx.x;
    int base = blockIdx.x * PS_CHUNK + t * PS_C;
    int vals[PS_C];
    int s = 0;
#pragma unroll
    for (int i = 0; i < PS_C; i++) {
        int idx = base + i;
        vals[i] = (idx < N) ? cnt[idx] : 0;
        s += vals[i];
    }
    sm[t] = s;
    __syncthreads();
    for (int off = 1; off < PS_T; off <<= 1) {
        int x = (t >= off) ? sm[t - off] : 0;
        __syncthreads();
        sm[t] += x;
        __syncthreads();
    }
    int run = blockSums[blockIdx.x] + sm[t] - s;   // exclusive prefix for this thread
#pragma unroll
    for (int i = 0; i < PS_C; i++) {
        int idx = base + i;
        if (idx < N) {
            row_ptr[idx] = run;
            run += vals[i];
            cnt[idx] = 0;   // reuse as fill counter in scatter
        }
    }
    if (blockIdx.x == 0 && t == 0) row_ptr[N] = E;
}

__global__ void scatter_kernel(const int* __restrict__ row, const int* __restrict__ col,
                               const float* __restrict__ val, const int* __restrict__ row_ptr,
                               int* __restrict__ fill, int2* __restrict__ cv, int E) {
    int e = blockIdx.x * blockDim.x + threadIdx.x;
    if (e < E) {
        int r = row[e];
        int p = row_ptr[r] + atomicAdd(&fill[r], 1);
        cv[p] = make_int2(col[e], __float_as_int(val[e]));
    }
}

// ---------------- weight conversions (MFMA-fragment order) ----------------

// W1 [512][256] f32 -> W1f bf16 in fragment order:
// idx = ((((nb*16 + t)*4 + nt)*64) + lane)*8 + j
// value = W1[k][n], n = nb*64 + nt*16 + (lane&15), k = t*32 + (lane>>4)*8 + j
__global__ void convert_w1(const float* __restrict__ W1, ushort_t* __restrict__ W1f) {
    int idx = blockIdx.x * 256 + threadIdx.x;   // 131072 total
    int j    = idx & 7;
    int lane = (idx >> 3) & 63;
    int nt   = (idx >> 9) & 3;
    int t    = (idx >> 11) & 15;
    int nb   = idx >> 15;
    int n = nb * 64 + nt * 16 + (lane & 15);
    int k = t * 32 + (lane >> 4) * 8 + j;
    W1f[idx] = f2b(W1[k * NHIDS + n]);
}

// W2 [256][40] f32 -> W2f bf16 fragment order (64 padded cols):
// idx = (((s*4 + nt)*64) + lane)*8 + j
// value = W2[k][n] (0 if n>=40), n = nt*16 + (lane&15), k = s*32 + (lane>>4)*8 + j
__global__ void convert_w2(const float* __restrict__ W2, ushort_t* __restrict__ W2f) {
    int idx = blockIdx.x * 256 + threadIdx.x;   // 16384 total
    int j    = idx & 7;
    int lane = (idx >> 3) & 63;
    int nt   = (idx >> 9) & 3;
    int s    = idx >> 11;
    int n = nt * 16 + (lane & 15);
    int k = s * 32 + (lane >> 4) * 8 + j;
    W2f[idx] = (n < NCLS) ? f2b(W2[k * NCLS + n]) : (ushort_t)0;
}

// ---------------- GEMM1: H1 = bf16(x @ W1)  via MFMA ----------------
// tile 64(M) x 256(N), BK=32 f32, 4 waves split N (wave w: n = w*64..+63).
// A staged raw-f32 via async global_load_lds(16B), double-buffered 2x8KB,
// one barrier per K-step, XOR-swizzled slots via pre-swizzled global source.
// B: one contiguous 1KB load per fragment from fragment-ordered W1f (L2-res).

#define G1_BM 64
#define G1_BK 32   // f32 per row-chunk = 128 B = 8 slots of 16 B

__global__ __launch_bounds__(256) void gemm1_kernel(const float* __restrict__ A,
                                                    const ushort_t* __restrict__ W1f,
                                                    ushort_t* __restrict__ H1, int M) {
    __shared__ float As[2][G1_BM * G1_BK];   // 2 x 8192 B
    int tid  = threadIdx.x;
    int wave = tid >> 6, lane = tid & 63;
    int quad = lane >> 4, ln = lane & 15;
    int m0 = blockIdx.x * G1_BM;

    // ---- staging geometry: wave w call c covers rows (w*2+c)*8 .. +7 ----
    int rloc0 = (wave * 2 + 0) * 8 + (lane >> 3);
    int rloc1 = (wave * 2 + 1) * 8 + (lane >> 3);
    int sslot = (lane & 7) ^ ((lane >> 3) & 7);
    int gr0 = m0 + rloc0; if (gr0 > M - 1) gr0 = M - 1;   // clamp: dup rows, never stored
    int gr1 = m0 + rloc1; if (gr1 > M - 1) gr1 = M - 1;
    const float* src0 = A + (size_t)gr0 * NFEATS + sslot * 4;
    const float* src1 = A + (size_t)gr1 * NFEATS + sslot * 4;
    float* dst0 = &As[0][(wave * 2 + 0) * 256];
    float* dst1 = &As[0][(wave * 2 + 1) * 256];
    float* dst0b = &As[1][(wave * 2 + 0) * 256];
    float* dst1b = &As[1][(wave * 2 + 1) * 256];

    // B fragment-ordered base for this wave: block (wave*16 + t) of 2048 elems
    const ushort_t* bbase = W1f + (size_t)(wave * 16) * 2048 + lane * 8;

    floatx4 acc[4][4] = {};

    // prologue: stage k-step 0 into buffer 0
    __builtin_amdgcn_global_load_lds(AS1C(src0), AS3(dst0), 16, 0, 0);
    __builtin_amdgcn_global_load_lds(AS1C(src1), AS3(dst1), 16, 0, 0);
    __syncthreads();

#pragma unroll 2
    for (int t = 0; t < NFEATS / G1_BK; ++t) {   // 16 K-steps
        int cur = t & 1;
        // issue next k-step's async stage into the other buffer
        if (t < NFEATS / G1_BK - 1) {
            const float* s0 = src0 + (t + 1) * G1_BK;
            const float* s1 = src1 + (t + 1) * G1_BK;
            if (cur == 0) {
                __builtin_amdgcn_global_load_lds(AS1C(s0), AS3(dst0b), 16, 0, 0);
                __builtin_amdgcn_global_load_lds(AS1C(s1), AS3(dst1b), 16, 0, 0);
            } else {
                __builtin_amdgcn_global_load_lds(AS1C(s0), AS3(dst0), 16, 0, 0);
                __builtin_amdgcn_global_load_lds(AS1C(s1), AS3(dst1), 16, 0, 0);
            }
        }
        // B fragments: contiguous 1KB coalesced loads from W1f
        frag8 bfr[4], af[4];
        const ushort_t* bstep = bbase + (size_t)t * 2048;
#pragma unroll
        for (int nt = 0; nt < 4; nt++)
            bfr[nt] = *(const frag8*)(bstep + nt * 512);
        // A fragments: swizzled ds_read f32 + packed cvt to bf16
#pragma unroll
        for (int mt = 0; mt < 4; mt++) {
            int R = mt * 16 + ln;
            int sw = R & 7;
            const float* base = &As[cur][R * G1_BK];
            float4 lo = *(const float4*)(base + (((2 * quad)     ^ sw) * 4));
            float4 hi = *(const float4*)(base + (((2 * quad + 1) ^ sw) * 4));
            union { frag8 f; uint_t u[4]; } fu;
            asm volatile("v_cvt_pk_bf16_f32 %0, %1, %2" : "=v"(fu.u[0]) : "v"(lo.x), "v"(lo.y));
            asm volatile("v_cvt_pk_bf16_f32 %0, %1, %2" : "=v"(fu.u[1]) : "v"(lo.z), "v"(lo.w));
            asm volatile("v_cvt_pk_bf16_f32 %0, %1, %2" : "=v"(fu.u[2]) : "v"(hi.x), "v"(hi.y));
            asm volatile("v_cvt_pk_bf16_f32 %0, %1, %2" : "=v"(fu.u[3]) : "v"(hi.z), "v"(hi.w));
            af[mt] = fu.f;
        }
#pragma unroll
        for (int mt = 0; mt < 4; mt++)
#pragma unroll
            for (int nt = 0; nt < 4; nt++)
                acc[mt][nt] = __builtin_amdgcn_mfma_f32_16x16x32_bf16(af[mt], bfr[nt], acc[mt][nt], 0, 0, 0);
        __syncthreads();
    }

    // C/D layout: col = ln, row = quad*4 + i
#pragma unroll
    for (int mt = 0; mt < 4; mt++) {
#pragma unroll
        for (int i = 0; i < 4; i++) {
            int m = m0 + mt * 16 + quad * 4 + i;
            if (m < M) {
#pragma unroll
                for (int nt = 0; nt < 4; nt++) {
                    H1[(size_t)m * NHIDS + wave * 64 + nt * 16 + ln] = f2b(acc[mt][nt][i]);
                }
            }
        }
    }
}

// ---------------- SpMM1: AGG = bf16(relu(A_hat @ H1 + b1)), F=256 ----------------
// one wave per row; 4-deep gather unroll for memory-level parallelism.

__global__ __launch_bounds__(256) void spmm1_kernel(const int* __restrict__ row_ptr,
                                                    const int2* __restrict__ cv,
                                                    const ushort_t* __restrict__ H1,
                                                    const float* __restrict__ b1,
                                                    ushort_t* __restrict__ AGG, int N) {
    int wave = threadIdx.x >> 6, lane = threadIdx.x & 63;
    int r = blockIdx.x * 4 + wave;
    if (r >= N) return;
    int s = row_ptr[r], e = row_ptr[r + 1];
    float a0 = 0.f, a1 = 0.f, a2 = 0.f, a3 = 0.f;
    int j = s;
    for (; j + 3 < e; j += 4) {
        int2 p0 = cv[j];
        int2 p1 = cv[j + 1];
        int2 p2 = cv[j + 2];
        int2 p3 = cv[j + 3];
        ushort4 h0 = *(const ushort4*)(H1 + (size_t)p0.x * NHIDS + lane * 4);
        ushort4 h1 = *(const ushort4*)(H1 + (size_t)p1.x * NHIDS + lane * 4);
        ushort4 h2 = *(const ushort4*)(H1 + (size_t)p2.x * NHIDS + lane * 4);
        ushort4 h3 = *(const ushort4*)(H1 + (size_t)p3.x * NHIDS + lane * 4);
        float v0 = __int_as_float(p0.y), v1 = __int_as_float(p1.y);
        float v2 = __int_as_float(p2.y), v3 = __int_as_float(p3.y);
        a0 += v0 * b2f(h0.x); a1 += v0 * b2f(h0.y); a2 += v0 * b2f(h0.z); a3 += v0 * b2f(h0.w);
        a0 += v1 * b2f(h1.x); a1 += v1 * b2f(h1.y); a2 += v1 * b2f(h1.z); a3 += v1 * b2f(h1.w);
        a0 += v2 * b2f(h2.x); a1 += v2 * b2f(h2.y); a2 += v2 * b2f(h2.z); a3 += v2 * b2f(h2.w);
        a0 += v3 * b2f(h3.x); a1 += v3 * b2f(h3.y); a2 += v3 * b2f(h3.z); a3 += v3 * b2f(h3.w);
    }
    for (; j < e; j++) {
        int2 p0 = cv[j];
        ushort4 h0 = *(const ushort4*)(H1 + (size_t)p0.x * NHIDS + lane * 4);
        float v0 = __int_as_float(p0.y);
        a0 += v0 * b2f(h0.x); a1 += v0 * b2f(h0.y); a2 += v0 * b2f(h0.z); a3 += v0 * b2f(h0.w);
    }
    float4 bb = *(const float4*)(b1 + lane * 4);
    a0 += bb.x; a1 += bb.y; a2 += bb.z; a3 += bb.w;
    ushort4 o;
    o.x = f2b(a0 > 0.f ? a0 : 0.f);
    o.y = f2b(a1 > 0.f ? a1 : 0.f);
    o.z = f2b(a2 > 0.f ? a2 : 0.f);
    o.w = f2b(a3 > 0.f ? a3 : 0.f);
    *(ushort4*)&AGG[(size_t)r * NHIDS + lane * 4] = o;
}

// ---------------- GEMM2: H2 = bf16(AGG @ W2) via MFMA, padded to 64 cols ----------------
// 256 threads = 4 waves; block covers 256 rows (wave w: rows w*64..w*64+63).
// A-frags direct from AGG (16B/lane); B-frags from fragment-ordered W2f
// (one contiguous 1KB load per fragment, 32 KB L1/L2-resident).

__global__ __launch_bounds__(256) void gemm2_kernel(const ushort_t* __restrict__ AGG,
                                                    const ushort_t* __restrict__ W2f,
                                                    ushort_t* __restrict__ H2, int M) {
    int tid  = threadIdx.x;
    int wave = tid >> 6, lane = tid & 63;
    int quad = lane >> 4, ln = lane & 15;
    int m0 = blockIdx.x * 256 + wave * 64;

    floatx4 acc[4][4] = {};
    frag8 zf = {};

#pragma unroll
    for (int s = 0; s < NHIDS / 32; s++) {
        int k0 = s * 32;
        frag8 af[4], bf[4];
#pragma unroll
        for (int mt = 0; mt < 4; mt++) {
            int m = m0 + mt * 16 + ln;
            af[mt] = (m < M) ? *(const frag8*)(AGG + (size_t)m * NHIDS + k0 + quad * 8) : zf;
        }
#pragma unroll
        for (int nt = 0; nt < 4; nt++)
            bf[nt] = *(const frag8*)(W2f + (size_t)(s * 4 + nt) * 512 + lane * 8);
#pragma unroll
        for (int mt = 0; mt < 4; mt++)
#pragma unroll
            for (int nt = 0; nt < 4; nt++)
                acc[mt][nt] = __builtin_amdgcn_mfma_f32_16x16x32_bf16(af[mt], bf[nt], acc[mt][nt], 0, 0, 0);
    }
    // C/D layout: col = ln, row = quad*4 + i
#pragma unroll
    for (int mt = 0; mt < 4; mt++) {
#pragma unroll
        for (int i = 0; i < 4; i++) {
            int m = m0 + mt * 16 + quad * 4 + i;
            if (m < M) {
#pragma unroll
                for (int nt = 0; nt < 4; nt++)
                    H2[(size_t)m * NCLSP + nt * 16 + ln] = f2b(acc[mt][nt][i]);
            }
        }
    }
}

// ---------------- SpMM2: out = A_hat @ H2 + b2, F=40 (padded reads of 64) ----------------
// 4-deep gather unroll.

__global__ __launch_bounds__(256) void spmm2_kernel(const int* __restrict__ row_ptr,
                                                    const int2* __restrict__ cv,
                                                    const ushort_t* __restrict__ H2,
                                                    const float* __restrict__ b2,
                                                    float* __restrict__ out, int N) {
    int wave = threadIdx.x >> 6, lane = threadIdx.x & 63;
    int half = lane >> 5, fl = lane & 31;
    int r = blockIdx.x * 8 + wave * 2 + half;
    if (r >= N) return;
    int s = row_ptr[r], e = row_ptr[r + 1];
    float a0 = 0.f, a1 = 0.f;
    int j = s;
    for (; j + 3 < e; j += 4) {
        int2 p0 = cv[j];
        int2 p1 = cv[j + 1];
        int2 p2 = cv[j + 2];
        int2 p3 = cv[j + 3];
        float v0 = __int_as_float(p0.y);
        float v1 = __int_as_float(p1.y);
        float v2 = __int_as_float(p2.y);
        float v3 = __int_as_float(p3.y);
        uint_t h0 = *(const uint_t*)(H2 + (size_t)p0.x * NCLSP + fl * 2);
        uint_t h1 = *(const uint_t*)(H2 + (size_t)p1.x * NCLSP + fl * 2);
        uint_t h2 = *(const uint_t*)(H2 + (size_t)p2.x * NCLSP + fl * 2);
        uint_t h3 = *(const uint_t*)(H2 + (size_t)p3.x * NCLSP + fl * 2);
        a0 += v0 * b2f((ushort_t)(h0 & 0xffff));
        a1 += v0 * b2f((ushort_t)(h0 >> 16));
        a0 += v1 * b2f((ushort_t)(h1 & 0xffff));
        a1 += v1 * b2f((ushort_t)(h1 >> 16));
        a0 += v2 * b2f((ushort_t)(h2 & 0xffff));
        a1 += v2 * b2f((ushort_t)(h2 >> 16));
        a0 += v3 * b2f((ushort_t)(h3 & 0xffff));
        a1 += v3 * b2f((ushort_t)(h3 >> 16));
    }
    for (; j < e; j++) {
        int2 p = cv[j];
        float v = __int_as_float(p.y);
        uint_t h = *(const uint_t*)(H2 + (size_t)p.x * NCLSP + fl * 2);
        a0 += v * b2f((ushort_t)(h & 0xffff));
        a1 += v * b2f((ushort_t)(h >> 16));
    }
    if (fl < NCLS / 2) {
        float2 o;
        o.x = a0 + b2[fl * 2];
        o.y = a1 + b2[fl * 2 + 1];
        *(float2*)(out + (size_t)r * NCLS + fl * 2) = o;
    }
}

// ---------------- launch ----------------

static inline size_t align256(size_t x) { return (x + 255) & ~(size_t)255; }

extern "C" void kernel_launch(void* const* d_in, const int* in_sizes, int n_in,
                              void* d_out, int out_size, void* d_ws, size_t ws_size,
                              hipStream_t stream) {
    const float* x        = (const float*)d_in[0];
    const float* W1       = (const float*)d_in[1];
    const float* b1       = (const float*)d_in[2];
    const float* W2       = (const float*)d_in[3];
    const float* b2       = (const float*)d_in[4];
    const int*   edge_row = (const int*)d_in[5];
    const int*   edge_col = (const int*)d_in[6];
    const float* edge_val = (const float*)d_in[7];
    float* out = (float*)d_out;

    int N = in_sizes[0] / NFEATS;  // 100000
    int E = in_sizes[5];           // 1700000

    char* w = (char*)d_ws;
    size_t off = 0;
    ushort_t* H1   = (ushort_t*)(w + off); off += align256((size_t)N * NHIDS * 2);
    ushort_t* AGG  = (ushort_t*)(w + off); off += align256((size_t)N * NHIDS * 2);
    ushort_t* H2   = (ushort_t*)(w + off); off += align256((size_t)N * NCLSP * 2);
    ushort_t* W1f  = (ushort_t*)(w + off); off += align256((size_t)NHIDS * NFEATS * 2);
    ushort_t* W2f  = (ushort_t*)(w + off); off += align256((size_t)NCLSP * NHIDS * 2);
    int*      row_ptr = (int*)(w + off); off += align256((size_t)(N + 1) * 4);
    int*      cnt     = (int*)(w + off); off += align256((size_t)N * 4);
    int*      blockSums = (int*)(w + off); off += align256((size_t)SS_T * 4);
    int2*     cv      = (int2*)(w + off); off += align256((size_t)E * 8);

    int scanB = (N + PS_CHUNK - 1) / PS_CHUNK;   // 98 for N=100000 (must be <= SS_T)

    // CSR build + weight conversion
    hipMemsetAsync(cnt, 0, (size_t)N * 4, stream);
    hist_kernel<<<(E + 255) / 256, 256, 0, stream>>>(edge_row, cnt, E);
    convert_w1<<<(NFEATS * NHIDS) / 256, 256, 0, stream>>>(W1, W1f);
    convert_w2<<<(NCLSP * NHIDS) / 256, 256, 0, stream>>>(W2, W2f);
    scan_partial_kernel<<<scanB, PS_T, 0, stream>>>(cnt, blockSums, N);
    scan_sums_kernel<<<1, SS_T, 0, stream>>>(blockSums, scanB);
    scan_finalize_kernel<<<scanB, PS_T, 0, stream>>>(cnt, blockSums, row_ptr, N, E);
    scatter_kernel<<<(E + 255) / 256, 256, 0, stream>>>(edge_row, edge_col, edge_val,
                                                        row_ptr, cnt, cv, E);

    // layer 1
    gemm1_kernel<<<(N + G1_BM - 1) / G1_BM, 256, 0, stream>>>(x, W1f, H1, N);
    spmm1_kernel<<<(N + 3) / 4, 256, 0, stream>>>(row_ptr, cv, H1, b1, AGG, N);

    // layer 2
    gemm2_kernel<<<(N + 255) / 256, 256, 0, stream>>>(AGG, W2f, H2, N);
    spmm2_kernel<<<(N + 7) / 8, 256, 0, stream>>>(row_ptr, cv, H2, b2, out, N);
}

// Round 6
// 665.467 us; speedup vs baseline: 1.1310x; 1.0083x over previous
//
#include <hip/hip_runtime.h>
#include <hip/hip_bf16.h>

// GCN forward: out = spmm(A, relu(spmm(A, x@W1)+b1) @ W2) + b2
// bf16 intermediate pipeline: GEMM1 + GEMM2 via MFMA bf16, H1/AGG/H2 stored bf16.
// R7-R9: gemm1 staging variants all ~125us, all pipes idle.
// R10: W1/W2 repacked to MFMA-fragment order (1KB coalesced B loads). spmm1
//      (123us, BW-bound 3.8TB/s random gather) now top; gemm1 ~110 hidden.
// R11: gemm1 K-loop de-drained: raw s_barrier + counted vmcnt (T3/T4 minimum).
//      4 LDS buffers, STAGE(t+3) + reg-prefetch LOADB(t+2) per step; in-order
//      vmcnt retirement makes the compiler's own B-reg wait cover stage t+1,
//      so no vmcnt(0) drain ever executes in the loop (one vmcnt(12) in
//      prologue). Also: H2 compacted 64->40 cols (spmm2 gather 218->136MB,
//      fl>=20 lanes retire), gemm2 drops the all-zero nt=3 tile.

#define NFEATS 512
#define NHIDS  256
#define NCLS   40

typedef unsigned short ushort_t;
typedef unsigned int uint_t;
typedef __attribute__((ext_vector_type(8))) short frag8;   // 8 bf16 = 16 B
typedef __attribute__((ext_vector_type(4))) float floatx4;

#define AS1C(p) ((__attribute__((address_space(1))) const void*)(p))
#define AS3(p)  ((__attribute__((address_space(3))) void*)(p))

__device__ __forceinline__ ushort_t f2b(float f) {
    uint_t u = __float_as_uint(f);
    uint_t r = (u + 0x7fffu + ((u >> 16) & 1u)) >> 16;   // RNE
    return (ushort_t)r;
}
__device__ __forceinline__ float b2f(ushort_t b) {
    return __uint_as_float((uint_t)b << 16);
}

// ---------------- CSR build ----------------

__global__ void hist_kernel(const int* __restrict__ row, int* __restrict__ cnt, int E) {
    int e = blockIdx.x * blockDim.x + threadIdx.x;
    if (e < E) atomicAdd(&cnt[row[e]], 1);
}

#define PS_T 256
#define PS_C 4
#define PS_CHUNK (PS_T * PS_C)   // 1024 elements per block

__global__ __launch_bounds__(PS_T) void scan_partial_kernel(const int* __restrict__ cnt,
                                                            int* __restrict__ blockSums, int N) {
    __shared__ int sm[PS_T];
    int t = threadIdx.x;
    int base = blockIdx.x * PS_CHUNK + t * PS_C;
    int s = 0;
    if (base + PS_C <= N) {
        int4 v = *(const int4*)(cnt + base);
        s = v.x + v.y + v.z + v.w;
    } else {
        for (int i = 0; i < PS_C; i++) if (base + i < N) s += cnt[base + i];
    }
    sm[t] = s;
    __syncthreads();
    for (int off = PS_T / 2; off > 0; off >>= 1) {
        if (t < off) sm[t] += sm[t + off];
        __syncthreads();
    }
    if (t == 0) blockSums[blockIdx.x] = sm[0];
}

#define SS_T 128   // must be >= number of scan blocks (98)
__global__ __launch_bounds__(SS_T) void scan_sums_kernel(int* __restrict__ blockSums, int B) {
    __shared__ int sm[SS_T];
    int t = threadIdx.x;
    int v = (t < B) ? blockSums[t] : 0;
    sm[t] = v;
    __syncthreads();
    for (int off = 1; off < SS_T; off <<= 1) {
        int x = (t >= off) ? sm[t - off] : 0;
        __syncthreads();
        sm[t] += x;
        __syncthreads();
    }
    if (t < B) blockSums[t] = sm[t] - v;   // exclusive
}

__global__ __launch_bounds__(PS_T) void scan_finalize_kernel(int* __restrict__ cnt,
                                                             const int* __restrict__ blockSums,
                                                             int* __restrict__ row_ptr, int N, int E) {
    __shared__ int sm[PS_T];
    int t = threadIdx.x;
    int base = blockIdx.x * PS_CHUNK + t * PS_C;
    int vals[PS_C];
    int s = 0;
#pragma unroll
    for (int i = 0; i < PS_C; i++) {
        int idx = base + i;
        vals[i] = (idx < N) ? cnt[idx] : 0;
        s += vals[i];
    }
    sm[t] = s;
    __syncthreads();
    for (int off = 1; off < PS_T; off <<= 1) {
        int x = (t >= off) ? sm[t - off] : 0;
        __syncthreads();
        sm[t] += x;
        __syncthreads();
    }
    int run = blockSums[blockIdx.x] + sm[t] - s;
#pragma unroll
    for (int i = 0; i < PS_C; i++) {
        int idx = base + i;
        if (idx < N) {
            row_ptr[idx] = run;
            run += vals[i];
            cnt[idx] = 0;   // reuse as fill counter in scatter
        }
    }
    if (blockIdx.x == 0 && t == 0) row_ptr[N] = E;
}

__global__ void scatter_kernel(const int* __restrict__ row, const int* __restrict__ col,
                               const float* __restrict__ val, const int* __restrict__ row_ptr,
                               int* __restrict__ fill, int2* __restrict__ cv, int E) {
    int e = blockIdx.x * blockDim.x + threadIdx.x;
    if (e < E) {
        int r = row[e];
        int p = row_ptr[r] + atomicAdd(&fill[r], 1);
        cv[p] = make_int2(col[e], __float_as_int(val[e]));
    }
}

// ---------------- weight conversions (MFMA-fragment order) ----------------

// W1 [512][256] f32 -> W1f bf16 fragment order.
__global__ void convert_w1(const float* __restrict__ W1, ushort_t* __restrict__ W1f) {
    int idx = blockIdx.x * 256 + threadIdx.x;   // 131072 total
    int j    = idx & 7;
    int lane = (idx >> 3) & 63;
    int nt   = (idx >> 9) & 3;
    int t    = (idx >> 11) & 15;
    int nb   = idx >> 15;
    int n = nb * 64 + nt * 16 + (lane & 15);
    int k = t * 32 + (lane >> 4) * 8 + j;
    W1f[idx] = f2b(W1[k * NHIDS + n]);
}

// W2 [256][40] f32 -> W2f bf16 fragment order (4 nt slots; nt=3 zero/unused).
__global__ void convert_w2(const float* __restrict__ W2, ushort_t* __restrict__ W2f) {
    int idx = blockIdx.x * 256 + threadIdx.x;   // 16384 total
    int j    = idx & 7;
    int lane = (idx >> 3) & 63;
    int nt   = (idx >> 9) & 3;
    int s    = idx >> 11;
    int n = nt * 16 + (lane & 15);
    int k = s * 32 + (lane >> 4) * 8 + j;
    W2f[idx] = (n < NCLS) ? f2b(W2[k * NCLS + n]) : (ushort_t)0;
}

// ---------------- GEMM1: H1 = bf16(x @ W1)  via MFMA, counted-vmcnt pipeline ----------------
// tile 64(M) x 256(N), BK=32 f32, 4 waves split N. A staged raw-f32 via async
// global_load_lds into 4 rotating buffers (stage lead 3); B reg-prefetch lead 2.
// Raw s_barrier per step (NO vmcnt(0) drain). In-order vmcnt retirement:
// per-step issue order [STAGE(t+3) ... LOADB(t+2)] guarantees the compiler's
// B(t)-register wait at step t retires s(t+1), so stage data is always landed
// before the barrier of the step that reads it. One manual vmcnt(12) in prologue.

#define G1_BM 64
#define G1_BK 32   // f32 per row-chunk = 128 B = 8 slots of 16 B

__global__ __launch_bounds__(256) void gemm1_kernel(const float* __restrict__ A,
                                                    const ushort_t* __restrict__ W1f,
                                                    ushort_t* __restrict__ H1, int M) {
    __shared__ float As[4][G1_BM * G1_BK];   // 4 x 8 KB
    int tid  = threadIdx.x;
    int wave = tid >> 6, lane = tid & 63;
    int quad = lane >> 4, ln = lane & 15;
    int m0 = blockIdx.x * G1_BM;

    // staging geometry: wave w call c covers rows (w*2+c)*8..+7; lane L:
    // local row g*8+(L>>3), dest slot L&7 (linear), source slot XOR-swizzled.
    int rloc0 = (wave * 2 + 0) * 8 + (lane >> 3);
    int rloc1 = (wave * 2 + 1) * 8 + (lane >> 3);
    int sslot = (lane & 7) ^ ((lane >> 3) & 7);
    int gr0 = m0 + rloc0; if (gr0 > M - 1) gr0 = M - 1;   // clamp: dup rows, never stored
    int gr1 = m0 + rloc1; if (gr1 > M - 1) gr1 = M - 1;
    const float* src0 = A + (size_t)gr0 * NFEATS + sslot * 4;
    const float* src1 = A + (size_t)gr1 * NFEATS + sslot * 4;

    const ushort_t* bbase = W1f + (size_t)(wave * 16) * 2048 + lane * 8;

    floatx4 acc[4][4] = {};
    frag8 bfrA[4], bfrB[4];

#define G1_STAGE(t) do { \
        float* d0_ = &As[(t) & 3][(wave * 2 + 0) * 256]; \
        float* d1_ = &As[(t) & 3][(wave * 2 + 1) * 256]; \
        __builtin_amdgcn_global_load_lds(AS1C(src0 + (t) * G1_BK), AS3(d0_), 16, 0, 0); \
        __builtin_amdgcn_global_load_lds(AS1C(src1 + (t) * G1_BK), AS3(d1_), 16, 0, 0); \
    } while (0)

#define G1_LOADB(t, dst) do { \
        const ushort_t* bs_ = bbase + (size_t)(t) * 2048; \
        dst[0] = *(const frag8*)(bs_); \
        dst[1] = *(const frag8*)(bs_ + 512); \
        dst[2] = *(const frag8*)(bs_ + 1024); \
        dst[3] = *(const frag8*)(bs_ + 1536); \
    } while (0)

    // prologue: order matters for in-order vmcnt coverage:
    // s0, s1, B0, s2, B1  ->  after-s0 count = 12
    G1_STAGE(0);
    G1_STAGE(1);
    G1_LOADB(0, bfrA);
    G1_STAGE(2);
    G1_LOADB(1, bfrB);
    asm volatile("s_waitcnt vmcnt(12)" ::: "memory");   // s0 landed
    __builtin_amdgcn_sched_barrier(0);

#pragma unroll
    for (int t = 0; t < NFEATS / G1_BK; ++t) {   // 16 K-steps
        __builtin_amdgcn_s_barrier();
        __builtin_amdgcn_sched_barrier(0);
        // A fragments: swizzled LDS f32 reads + packed cvt to bf16
        frag8 af[4];
#pragma unroll
        for (int mt = 0; mt < 4; mt++) {
            int R = mt * 16 + ln;
            int sw = R & 7;
            const float* base = &As[t & 3][R * G1_BK];
            float4 lo = *(const float4*)(base + (((2 * quad)     ^ sw) * 4));
            float4 hi = *(const float4*)(base + (((2 * quad + 1) ^ sw) * 4));
            union { frag8 f; uint_t u[4]; } fu;
            asm volatile("v_cvt_pk_bf16_f32 %0, %1, %2" : "=v"(fu.u[0]) : "v"(lo.x), "v"(lo.y));
            asm volatile("v_cvt_pk_bf16_f32 %0, %1, %2" : "=v"(fu.u[1]) : "v"(lo.z), "v"(lo.w));
            asm volatile("v_cvt_pk_bf16_f32 %0, %1, %2" : "=v"(fu.u[2]) : "v"(hi.x), "v"(hi.y));
            asm volatile("v_cvt_pk_bf16_f32 %0, %1, %2" : "=v"(fu.u[3]) : "v"(hi.z), "v"(hi.w));
            af[mt] = fu.f;
        }
        // stage lead-3 (before B loads: keeps s(t+3) older than B(t+2))
        if (t < 13) G1_STAGE(t + 3);
        __builtin_amdgcn_sched_barrier(0);
        if ((t & 1) == 0) {
#pragma unroll
            for (int mt = 0; mt < 4; mt++)
#pragma unroll
                for (int nt = 0; nt < 4; nt++)
                    acc[mt][nt] = __builtin_amdgcn_mfma_f32_16x16x32_bf16(af[mt], bfrA[nt], acc[mt][nt], 0, 0, 0);
            if (t < 14) G1_LOADB(t + 2, bfrA);   // WAR on bfrA orders this after MFMAs
        } else {
#pragma unroll
            for (int mt = 0; mt < 4; mt++)
#pragma unroll
                for (int nt = 0; nt < 4; nt++)
                    acc[mt][nt] = __builtin_amdgcn_mfma_f32_16x16x32_bf16(af[mt], bfrB[nt], acc[mt][nt], 0, 0, 0);
            if (t < 14) G1_LOADB(t + 2, bfrB);
        }
    }

    // C/D layout: col = ln, row = quad*4 + i
#pragma unroll
    for (int mt = 0; mt < 4; mt++) {
#pragma unroll
        for (int i = 0; i < 4; i++) {
            int m = m0 + mt * 16 + quad * 4 + i;
            if (m < M) {
#pragma unroll
                for (int nt = 0; nt < 4; nt++) {
                    H1[(size_t)m * NHIDS + wave * 64 + nt * 16 + ln] = f2b(acc[mt][nt][i]);
                }
            }
        }
    }
#undef G1_STAGE
#undef G1_LOADB
}

// ---------------- SpMM1: AGG = bf16(relu(A_hat @ H1 + b1)), F=256 ----------------

__global__ __launch_bounds__(256) void spmm1_kernel(const int* __restrict__ row_ptr,
                                                    const int2* __restrict__ cv,
                                                    const ushort_t* __restrict__ H1,
                                                    const float* __restrict__ b1,
                                                    ushort_t* __restrict__ AGG, int N) {
    int wave = threadIdx.x >> 6, lane = threadIdx.x & 63;
    int r = blockIdx.x * 4 + wave;
    if (r >= N) return;
    int s = row_ptr[r], e = row_ptr[r + 1];
    float a0 = 0.f, a1 = 0.f, a2 = 0.f, a3 = 0.f;
    int j = s;
    for (; j + 3 < e; j += 4) {
        int2 p0 = cv[j];
        int2 p1 = cv[j + 1];
        int2 p2 = cv[j + 2];
        int2 p3 = cv[j + 3];
        ushort4 h0 = *(const ushort4*)(H1 + (size_t)p0.x * NHIDS + lane * 4);
        ushort4 h1 = *(const ushort4*)(H1 + (size_t)p1.x * NHIDS + lane * 4);
        ushort4 h2 = *(const ushort4*)(H1 + (size_t)p2.x * NHIDS + lane * 4);
        ushort4 h3 = *(const ushort4*)(H1 + (size_t)p3.x * NHIDS + lane * 4);
        float v0 = __int_as_float(p0.y), v1 = __int_as_float(p1.y);
        float v2 = __int_as_float(p2.y), v3 = __int_as_float(p3.y);
        a0 += v0 * b2f(h0.x); a1 += v0 * b2f(h0.y); a2 += v0 * b2f(h0.z); a3 += v0 * b2f(h0.w);
        a0 += v1 * b2f(h1.x); a1 += v1 * b2f(h1.y); a2 += v1 * b2f(h1.z); a3 += v1 * b2f(h1.w);
        a0 += v2 * b2f(h2.x); a1 += v2 * b2f(h2.y); a2 += v2 * b2f(h2.z); a3 += v2 * b2f(h2.w);
        a0 += v3 * b2f(h3.x); a1 += v3 * b2f(h3.y); a2 += v3 * b2f(h3.z); a3 += v3 * b2f(h3.w);
    }
    for (; j < e; j++) {
        int2 p0 = cv[j];
        ushort4 h0 = *(const ushort4*)(H1 + (size_t)p0.x * NHIDS + lane * 4);
        float v0 = __int_as_float(p0.y);
        a0 += v0 * b2f(h0.x); a1 += v0 * b2f(h0.y); a2 += v0 * b2f(h0.z); a3 += v0 * b2f(h0.w);
    }
    float4 bb = *(const float4*)(b1 + lane * 4);
    a0 += bb.x; a1 += bb.y; a2 += bb.z; a3 += bb.w;
    ushort4 o;
    o.x = f2b(a0 > 0.f ? a0 : 0.f);
    o.y = f2b(a1 > 0.f ? a1 : 0.f);
    o.z = f2b(a2 > 0.f ? a2 : 0.f);
    o.w = f2b(a3 > 0.f ? a3 : 0.f);
    *(ushort4*)&AGG[(size_t)r * NHIDS + lane * 4] = o;
}

// ---------------- GEMM2: H2 = bf16(AGG @ W2), compact 40-col output ----------------
// 256 threads = 4 waves; block covers 256 rows. 3 n-tiles (48 cols >= 40);
// A-frags direct from AGG, B-frags from fragment-ordered W2f (L1/L2-resident).

__global__ __launch_bounds__(256) void gemm2_kernel(const ushort_t* __restrict__ AGG,
                                                    const ushort_t* __restrict__ W2f,
                                                    ushort_t* __restrict__ H2, int M) {
    int tid  = threadIdx.x;
    int wave = tid >> 6, lane = tid & 63;
    int quad = lane >> 4, ln = lane & 15;
    int m0 = blockIdx.x * 256 + wave * 64;

    floatx4 acc[4][3] = {};
    frag8 zf = {};

#pragma unroll
    for (int s = 0; s < NHIDS / 32; s++) {
        int k0 = s * 32;
        frag8 af[4], bf[3];
#pragma unroll
        for (int mt = 0; mt < 4; mt++) {
            int m = m0 + mt * 16 + ln;
            af[mt] = (m < M) ? *(const frag8*)(AGG + (size_t)m * NHIDS + k0 + quad * 8) : zf;
        }
#pragma unroll
        for (int nt = 0; nt < 3; nt++)
            bf[nt] = *(const frag8*)(W2f + (size_t)(s * 4 + nt) * 512 + lane * 8);
#pragma unroll
        for (int mt = 0; mt < 4; mt++)
#pragma unroll
            for (int nt = 0; nt < 3; nt++)
                acc[mt][nt] = __builtin_amdgcn_mfma_f32_16x16x32_bf16(af[mt], bf[nt], acc[mt][nt], 0, 0, 0);
    }
    // C/D layout: col = ln, row = quad*4 + i; compact stride NCLS=40
#pragma unroll
    for (int mt = 0; mt < 4; mt++) {
#pragma unroll
        for (int i = 0; i < 4; i++) {
            int m = m0 + mt * 16 + quad * 4 + i;
            if (m < M) {
                H2[(size_t)m * NCLS + ln]      = f2b(acc[mt][0][i]);
                H2[(size_t)m * NCLS + 16 + ln] = f2b(acc[mt][1][i]);
                if (ln < 8)
                    H2[(size_t)m * NCLS + 32 + ln] = f2b(acc[mt][2][i]);
            }
        }
    }
}

// ---------------- SpMM2: out = A_hat @ H2 + b2, F=40 compact ----------------
// 2 rows/wave, lanes fl<20 active (80 B per edge-gather); 4-deep unroll.

__global__ __launch_bounds__(256) void spmm2_kernel(const int* __restrict__ row_ptr,
                                                    const int2* __restrict__ cv,
                                                    const ushort_t* __restrict__ H2,
                                                    const float* __restrict__ b2,
                                                    float* __restrict__ out, int N) {
    int wave = threadIdx.x >> 6, lane = threadIdx.x & 63;
    int half = lane >> 5, fl = lane & 31;
    int r = blockIdx.x * 8 + wave * 2 + half;
    if (r >= N || fl >= NCLS / 2) return;
    int s = row_ptr[r], e = row_ptr[r + 1];
    float a0 = 0.f, a1 = 0.f;
    int j = s;
    for (; j + 3 < e; j += 4) {
        int2 p0 = cv[j];
        int2 p1 = cv[j + 1];
        int2 p2 = cv[j + 2];
        int2 p3 = cv[j + 3];
        float v0 = __int_as_float(p0.y);
        float v1 = __int_as_float(p1.y);
        float v2 = __int_as_float(p2.y);
        float v3 = __int_as_float(p3.y);
        uint_t h0 = *(const uint_t*)(H2 + (size_t)p0.x * NCLS + fl * 2);
        uint_t h1 = *(const uint_t*)(H2 + (size_t)p1.x * NCLS + fl * 2);
        uint_t h2 = *(const uint_t*)(H2 + (size_t)p2.x * NCLS + fl * 2);
        uint_t h3 = *(const uint_t*)(H2 + (size_t)p3.x * NCLS + fl * 2);
        a0 += v0 * b2f((ushort_t)(h0 & 0xffff));
        a1 += v0 * b2f((ushort_t)(h0 >> 16));
        a0 += v1 * b2f((ushort_t)(h1 & 0xffff));
        a1 += v1 * b2f((ushort_t)(h1 >> 16));
        a0 += v2 * b2f((ushort_t)(h2 & 0xffff));
        a1 += v2 * b2f((ushort_t)(h2 >> 16));
        a0 += v3 * b2f((ushort_t)(h3 & 0xffff));
        a1 += v3 * b2f((ushort_t)(h3 >> 16));
    }
    for (; j < e; j++) {
        int2 p = cv[j];
        float v = __int_as_float(p.y);
        uint_t h = *(const uint_t*)(H2 + (size_t)p.x * NCLS + fl * 2);
        a0 += v * b2f((ushort_t)(h & 0xffff));
        a1 += v * b2f((ushort_t)(h >> 16));
    }
    float2 o;
    o.x = a0 + b2[fl * 2];
    o.y = a1 + b2[fl * 2 + 1];
    *(float2*)(out + (size_t)r * NCLS + fl * 2) = o;
}

// ---------------- launch ----------------

static inline size_t align256(size_t x) { return (x + 255) & ~(size_t)255; }

extern "C" void kernel_launch(void* const* d_in, const int* in_sizes, int n_in,
                              void* d_out, int out_size, void* d_ws, size_t ws_size,
                              hipStream_t stream) {
    const float* x        = (const float*)d_in[0];
    const float* W1       = (const float*)d_in[1];
    const float* b1       = (const float*)d_in[2];
    const float* W2       = (const float*)d_in[3];
    const float* b2       = (const float*)d_in[4];
    const int*   edge_row = (const int*)d_in[5];
    const int*   edge_col = (const int*)d_in[6];
    const float* edge_val = (const float*)d_in[7];
    float* out = (float*)d_out;

    int N = in_sizes[0] / NFEATS;  // 100000
    int E = in_sizes[5];           // 1700000

    char* w = (char*)d_ws;
    size_t off = 0;
    ushort_t* H1   = (ushort_t*)(w + off); off += align256((size_t)N * NHIDS * 2);
    ushort_t* AGG  = (ushort_t*)(w + off); off += align256((size_t)N * NHIDS * 2);
    ushort_t* H2   = (ushort_t*)(w + off); off += align256((size_t)N * NCLS * 2);
    ushort_t* W1f  = (ushort_t*)(w + off); off += align256((size_t)NHIDS * NFEATS * 2);
    ushort_t* W2f  = (ushort_t*)(w + off); off += align256((size_t)64 * NHIDS * 2);
    int*      row_ptr = (int*)(w + off); off += align256((size_t)(N + 1) * 4);
    int*      cnt     = (int*)(w + off); off += align256((size_t)N * 4);
    int*      blockSums = (int*)(w + off); off += align256((size_t)SS_T * 4);
    int2*     cv      = (int2*)(w + off); off += align256((size_t)E * 8);

    int scanB = (N + PS_CHUNK - 1) / PS_CHUNK;   // 98 for N=100000 (must be <= SS_T)

    // CSR build + weight conversion
    hipMemsetAsync(cnt, 0, (size_t)N * 4, stream);
    hist_kernel<<<(E + 255) / 256, 256, 0, stream>>>(edge_row, cnt, E);
    convert_w1<<<(NFEATS * NHIDS) / 256, 256, 0, stream>>>(W1, W1f);
    convert_w2<<<(64 * NHIDS) / 256, 256, 0, stream>>>(W2, W2f);
    scan_partial_kernel<<<scanB, PS_T, 0, stream>>>(cnt, blockSums, N);
    scan_sums_kernel<<<1, SS_T, 0, stream>>>(blockSums, scanB);
    scan_finalize_kernel<<<scanB, PS_T, 0, stream>>>(cnt, blockSums, row_ptr, N, E);
    scatter_kernel<<<(E + 255) / 256, 256, 0, stream>>>(edge_row, edge_col, edge_val,
                                                        row_ptr, cnt, cv, E);

    // layer 1
    gemm1_kernel<<<(N + G1_BM - 1) / G1_BM, 256, 0, stream>>>(x, W1f, H1, N);
    spmm1_kernel<<<(N + 3) / 4, 256, 0, stream>>>(row_ptr, cv, H1, b1, AGG, N);

    // layer 2
    gemm2_kernel<<<(N + 255) / 256, 256, 0, stream>>>(AGG, W2f, H2, N);
    spmm2_kernel<<<(N + 7) / 8, 256, 0, stream>>>(row_ptr, cv, H2, b2, out, N);
}

// Round 7
// 660.056 us; speedup vs baseline: 1.1403x; 1.0082x over previous
//
#include <hip/hip_runtime.h>
#include <hip/hip_bf16.h>

// GCN forward: out = spmm(A, relu(spmm(A, x@W1)+b1) @ W2) + b2
// bf16 intermediate pipeline: GEMM1 + GEMM2 via MFMA bf16, H1/AGG/H2 stored bf16.
// R10: W1/W2 repacked to MFMA-fragment order. R11: gemm1 counted-vmcnt pipeline,
//      H2 compacted to 40 cols. 665us; spmm1 (123us) dominant.
// R12: spmm1 FETCH=404MB == 8 XCD x 51MB H1 -> bytes at structural floor;
//      BW only 3.7 TB/s EA (L3-servable, ceiling ~6.3+) with 4 gathers in
//      flight/wave => MLP-limited. Gather unroll 4->8 in spmm1 & spmm2
//      (VGPR ~50, still <=64 so occupancy tier unchanged).

#define NFEATS 512
#define NHIDS  256
#define NCLS   40

typedef unsigned short ushort_t;
typedef unsigned int uint_t;
typedef __attribute__((ext_vector_type(8))) short frag8;   // 8 bf16 = 16 B
typedef __attribute__((ext_vector_type(4))) float floatx4;

#define AS1C(p) ((__attribute__((address_space(1))) const void*)(p))
#define AS3(p)  ((__attribute__((address_space(3))) void*)(p))

__device__ __forceinline__ ushort_t f2b(float f) {
    uint_t u = __float_as_uint(f);
    uint_t r = (u + 0x7fffu + ((u >> 16) & 1u)) >> 16;   // RNE
    return (ushort_t)r;
}
__device__ __forceinline__ float b2f(ushort_t b) {
    return __uint_as_float((uint_t)b << 16);
}

// ---------------- CSR build ----------------

__global__ void hist_kernel(const int* __restrict__ row, int* __restrict__ cnt, int E) {
    int e = blockIdx.x * blockDim.x + threadIdx.x;
    if (e < E) atomicAdd(&cnt[row[e]], 1);
}

#define PS_T 256
#define PS_C 4
#define PS_CHUNK (PS_T * PS_C)   // 1024 elements per block

__global__ __launch_bounds__(PS_T) void scan_partial_kernel(const int* __restrict__ cnt,
                                                            int* __restrict__ blockSums, int N) {
    __shared__ int sm[PS_T];
    int t = threadIdx.x;
    int base = blockIdx.x * PS_CHUNK + t * PS_C;
    int s = 0;
    if (base + PS_C <= N) {
        int4 v = *(const int4*)(cnt + base);
        s = v.x + v.y + v.z + v.w;
    } else {
        for (int i = 0; i < PS_C; i++) if (base + i < N) s += cnt[base + i];
    }
    sm[t] = s;
    __syncthreads();
    for (int off = PS_T / 2; off > 0; off >>= 1) {
        if (t < off) sm[t] += sm[t + off];
        __syncthreads();
    }
    if (t == 0) blockSums[blockIdx.x] = sm[0];
}

#define SS_T 128   // must be >= number of scan blocks (98)
__global__ __launch_bounds__(SS_T) void scan_sums_kernel(int* __restrict__ blockSums, int B) {
    __shared__ int sm[SS_T];
    int t = threadIdx.x;
    int v = (t < B) ? blockSums[t] : 0;
    sm[t] = v;
    __syncthreads();
    for (int off = 1; off < SS_T; off <<= 1) {
        int x = (t >= off) ? sm[t - off] : 0;
        __syncthreads();
        sm[t] += x;
        __syncthreads();
    }
    if (t < B) blockSums[t] = sm[t] - v;   // exclusive
}

__global__ __launch_bounds__(PS_T) void scan_finalize_kernel(int* __restrict__ cnt,
                                                             const int* __restrict__ blockSums,
                                                             int* __restrict__ row_ptr, int N, int E) {
    __shared__ int sm[PS_T];
    int t = threadIdx.x;
    int base = blockIdx.x * PS_CHUNK + t * PS_C;
    int vals[PS_C];
    int s = 0;
#pragma unroll
    for (int i = 0; i < PS_C; i++) {
        int idx = base + i;
        vals[i] = (idx < N) ? cnt[idx] : 0;
        s += vals[i];
    }
    sm[t] = s;
    __syncthreads();
    for (int off = 1; off < PS_T; off <<= 1) {
        int x = (t >= off) ? sm[t - off] : 0;
        __syncthreads();
        sm[t] += x;
        __syncthreads();
    }
    int run = blockSums[blockIdx.x] + sm[t] - s;
#pragma unroll
    for (int i = 0; i < PS_C; i++) {
        int idx = base + i;
        if (idx < N) {
            row_ptr[idx] = run;
            run += vals[i];
            cnt[idx] = 0;   // reuse as fill counter in scatter
        }
    }
    if (blockIdx.x == 0 && t == 0) row_ptr[N] = E;
}

__global__ void scatter_kernel(const int* __restrict__ row, const int* __restrict__ col,
                               const float* __restrict__ val, const int* __restrict__ row_ptr,
                               int* __restrict__ fill, int2* __restrict__ cv, int E) {
    int e = blockIdx.x * blockDim.x + threadIdx.x;
    if (e < E) {
        int r = row[e];
        int p = row_ptr[r] + atomicAdd(&fill[r], 1);
        cv[p] = make_int2(col[e], __float_as_int(val[e]));
    }
}

// ---------------- weight conversions (MFMA-fragment order) ----------------

// W1 [512][256] f32 -> W1f bf16 fragment order.
__global__ void convert_w1(const float* __restrict__ W1, ushort_t* __restrict__ W1f) {
    int idx = blockIdx.x * 256 + threadIdx.x;   // 131072 total
    int j    = idx & 7;
    int lane = (idx >> 3) & 63;
    int nt   = (idx >> 9) & 3;
    int t    = (idx >> 11) & 15;
    int nb   = idx >> 15;
    int n = nb * 64 + nt * 16 + (lane & 15);
    int k = t * 32 + (lane >> 4) * 8 + j;
    W1f[idx] = f2b(W1[k * NHIDS + n]);
}

// W2 [256][40] f32 -> W2f bf16 fragment order (4 nt slots; nt=3 zero/unused).
__global__ void convert_w2(const float* __restrict__ W2, ushort_t* __restrict__ W2f) {
    int idx = blockIdx.x * 256 + threadIdx.x;   // 16384 total
    int j    = idx & 7;
    int lane = (idx >> 3) & 63;
    int nt   = (idx >> 9) & 3;
    int s    = idx >> 11;
    int n = nt * 16 + (lane & 15);
    int k = s * 32 + (lane >> 4) * 8 + j;
    W2f[idx] = (n < NCLS) ? f2b(W2[k * NCLS + n]) : (ushort_t)0;
}

// ---------------- GEMM1: H1 = bf16(x @ W1)  via MFMA, counted-vmcnt pipeline ----------------

#define G1_BM 64
#define G1_BK 32   // f32 per row-chunk = 128 B = 8 slots of 16 B

__global__ __launch_bounds__(256) void gemm1_kernel(const float* __restrict__ A,
                                                    const ushort_t* __restrict__ W1f,
                                                    ushort_t* __restrict__ H1, int M) {
    __shared__ float As[4][G1_BM * G1_BK];   // 4 x 8 KB
    int tid  = threadIdx.x;
    int wave = tid >> 6, lane = tid & 63;
    int quad = lane >> 4, ln = lane & 15;
    int m0 = blockIdx.x * G1_BM;

    int rloc0 = (wave * 2 + 0) * 8 + (lane >> 3);
    int rloc1 = (wave * 2 + 1) * 8 + (lane >> 3);
    int sslot = (lane & 7) ^ ((lane >> 3) & 7);
    int gr0 = m0 + rloc0; if (gr0 > M - 1) gr0 = M - 1;   // clamp: dup rows, never stored
    int gr1 = m0 + rloc1; if (gr1 > M - 1) gr1 = M - 1;
    const float* src0 = A + (size_t)gr0 * NFEATS + sslot * 4;
    const float* src1 = A + (size_t)gr1 * NFEATS + sslot * 4;

    const ushort_t* bbase = W1f + (size_t)(wave * 16) * 2048 + lane * 8;

    floatx4 acc[4][4] = {};
    frag8 bfrA[4], bfrB[4];

#define G1_STAGE(t) do { \
        float* d0_ = &As[(t) & 3][(wave * 2 + 0) * 256]; \
        float* d1_ = &As[(t) & 3][(wave * 2 + 1) * 256]; \
        __builtin_amdgcn_global_load_lds(AS1C(src0 + (t) * G1_BK), AS3(d0_), 16, 0, 0); \
        __builtin_amdgcn_global_load_lds(AS1C(src1 + (t) * G1_BK), AS3(d1_), 16, 0, 0); \
    } while (0)

#define G1_LOADB(t, dst) do { \
        const ushort_t* bs_ = bbase + (size_t)(t) * 2048; \
        dst[0] = *(const frag8*)(bs_); \
        dst[1] = *(const frag8*)(bs_ + 512); \
        dst[2] = *(const frag8*)(bs_ + 1024); \
        dst[3] = *(const frag8*)(bs_ + 1536); \
    } while (0)

    // prologue: s0, s1, B0, s2, B1  ->  after-s0 count = 12
    G1_STAGE(0);
    G1_STAGE(1);
    G1_LOADB(0, bfrA);
    G1_STAGE(2);
    G1_LOADB(1, bfrB);
    asm volatile("s_waitcnt vmcnt(12)" ::: "memory");   // s0 landed
    __builtin_amdgcn_sched_barrier(0);

#pragma unroll
    for (int t = 0; t < NFEATS / G1_BK; ++t) {   // 16 K-steps
        __builtin_amdgcn_s_barrier();
        __builtin_amdgcn_sched_barrier(0);
        frag8 af[4];
#pragma unroll
        for (int mt = 0; mt < 4; mt++) {
            int R = mt * 16 + ln;
            int sw = R & 7;
            const float* base = &As[t & 3][R * G1_BK];
            float4 lo = *(const float4*)(base + (((2 * quad)     ^ sw) * 4));
            float4 hi = *(const float4*)(base + (((2 * quad + 1) ^ sw) * 4));
            union { frag8 f; uint_t u[4]; } fu;
            asm volatile("v_cvt_pk_bf16_f32 %0, %1, %2" : "=v"(fu.u[0]) : "v"(lo.x), "v"(lo.y));
            asm volatile("v_cvt_pk_bf16_f32 %0, %1, %2" : "=v"(fu.u[1]) : "v"(lo.z), "v"(lo.w));
            asm volatile("v_cvt_pk_bf16_f32 %0, %1, %2" : "=v"(fu.u[2]) : "v"(hi.x), "v"(hi.y));
            asm volatile("v_cvt_pk_bf16_f32 %0, %1, %2" : "=v"(fu.u[3]) : "v"(hi.z), "v"(hi.w));
            af[mt] = fu.f;
        }
        if (t < 13) G1_STAGE(t + 3);
        __builtin_amdgcn_sched_barrier(0);
        if ((t & 1) == 0) {
#pragma unroll
            for (int mt = 0; mt < 4; mt++)
#pragma unroll
                for (int nt = 0; nt < 4; nt++)
                    acc[mt][nt] = __builtin_amdgcn_mfma_f32_16x16x32_bf16(af[mt], bfrA[nt], acc[mt][nt], 0, 0, 0);
            if (t < 14) G1_LOADB(t + 2, bfrA);
        } else {
#pragma unroll
            for (int mt = 0; mt < 4; mt++)
#pragma unroll
                for (int nt = 0; nt < 4; nt++)
                    acc[mt][nt] = __builtin_amdgcn_mfma_f32_16x16x32_bf16(af[mt], bfrB[nt], acc[mt][nt], 0, 0, 0);
            if (t < 14) G1_LOADB(t + 2, bfrB);
        }
    }

    // C/D layout: col = ln, row = quad*4 + i
#pragma unroll
    for (int mt = 0; mt < 4; mt++) {
#pragma unroll
        for (int i = 0; i < 4; i++) {
            int m = m0 + mt * 16 + quad * 4 + i;
            if (m < M) {
#pragma unroll
                for (int nt = 0; nt < 4; nt++) {
                    H1[(size_t)m * NHIDS + wave * 64 + nt * 16 + ln] = f2b(acc[mt][nt][i]);
                }
            }
        }
    }
#undef G1_STAGE
#undef G1_LOADB
}

// ---------------- SpMM1: AGG = bf16(relu(A_hat @ H1 + b1)), F=256 ----------------
// one wave per row; 8-deep gather unroll (MLP: 8 x 512B in flight per wave).

__global__ __launch_bounds__(256) void spmm1_kernel(const int* __restrict__ row_ptr,
                                                    const int2* __restrict__ cv,
                                                    const ushort_t* __restrict__ H1,
                                                    const float* __restrict__ b1,
                                                    ushort_t* __restrict__ AGG, int N) {
    int wave = threadIdx.x >> 6, lane = threadIdx.x & 63;
    int r = blockIdx.x * 4 + wave;
    if (r >= N) return;
    int s = row_ptr[r], e = row_ptr[r + 1];
    float a0 = 0.f, a1 = 0.f, a2 = 0.f, a3 = 0.f;
    int j = s;
    for (; j + 7 < e; j += 8) {
        int2 p[8];
        ushort4 h[8];
#pragma unroll
        for (int q = 0; q < 8; q++) p[q] = cv[j + q];
#pragma unroll
        for (int q = 0; q < 8; q++)
            h[q] = *(const ushort4*)(H1 + (size_t)p[q].x * NHIDS + lane * 4);
#pragma unroll
        for (int q = 0; q < 8; q++) {
            float v = __int_as_float(p[q].y);
            a0 += v * b2f(h[q].x);
            a1 += v * b2f(h[q].y);
            a2 += v * b2f(h[q].z);
            a3 += v * b2f(h[q].w);
        }
    }
    for (; j + 3 < e; j += 4) {
        int2 p[4];
        ushort4 h[4];
#pragma unroll
        for (int q = 0; q < 4; q++) p[q] = cv[j + q];
#pragma unroll
        for (int q = 0; q < 4; q++)
            h[q] = *(const ushort4*)(H1 + (size_t)p[q].x * NHIDS + lane * 4);
#pragma unroll
        for (int q = 0; q < 4; q++) {
            float v = __int_as_float(p[q].y);
            a0 += v * b2f(h[q].x);
            a1 += v * b2f(h[q].y);
            a2 += v * b2f(h[q].z);
            a3 += v * b2f(h[q].w);
        }
    }
    for (; j < e; j++) {
        int2 p0 = cv[j];
        ushort4 h0 = *(const ushort4*)(H1 + (size_t)p0.x * NHIDS + lane * 4);
        float v0 = __int_as_float(p0.y);
        a0 += v0 * b2f(h0.x); a1 += v0 * b2f(h0.y); a2 += v0 * b2f(h0.z); a3 += v0 * b2f(h0.w);
    }
    float4 bb = *(const float4*)(b1 + lane * 4);
    a0 += bb.x; a1 += bb.y; a2 += bb.z; a3 += bb.w;
    ushort4 o;
    o.x = f2b(a0 > 0.f ? a0 : 0.f);
    o.y = f2b(a1 > 0.f ? a1 : 0.f);
    o.z = f2b(a2 > 0.f ? a2 : 0.f);
    o.w = f2b(a3 > 0.f ? a3 : 0.f);
    *(ushort4*)&AGG[(size_t)r * NHIDS + lane * 4] = o;
}

// ---------------- GEMM2: H2 = bf16(AGG @ W2), compact 40-col output ----------------

__global__ __launch_bounds__(256) void gemm2_kernel(const ushort_t* __restrict__ AGG,
                                                    const ushort_t* __restrict__ W2f,
                                                    ushort_t* __restrict__ H2, int M) {
    int tid  = threadIdx.x;
    int wave = tid >> 6, lane = tid & 63;
    int quad = lane >> 4, ln = lane & 15;
    int m0 = blockIdx.x * 256 + wave * 64;

    floatx4 acc[4][3] = {};
    frag8 zf = {};

#pragma unroll
    for (int s = 0; s < NHIDS / 32; s++) {
        int k0 = s * 32;
        frag8 af[4], bf[3];
#pragma unroll
        for (int mt = 0; mt < 4; mt++) {
            int m = m0 + mt * 16 + ln;
            af[mt] = (m < M) ? *(const frag8*)(AGG + (size_t)m * NHIDS + k0 + quad * 8) : zf;
        }
#pragma unroll
        for (int nt = 0; nt < 3; nt++)
            bf[nt] = *(const frag8*)(W2f + (size_t)(s * 4 + nt) * 512 + lane * 8);
#pragma unroll
        for (int mt = 0; mt < 4; mt++)
#pragma unroll
            for (int nt = 0; nt < 3; nt++)
                acc[mt][nt] = __builtin_amdgcn_mfma_f32_16x16x32_bf16(af[mt], bf[nt], acc[mt][nt], 0, 0, 0);
    }
    // C/D layout: col = ln, row = quad*4 + i; compact stride NCLS=40
#pragma unroll
    for (int mt = 0; mt < 4; mt++) {
#pragma unroll
        for (int i = 0; i < 4; i++) {
            int m = m0 + mt * 16 + quad * 4 + i;
            if (m < M) {
                H2[(size_t)m * NCLS + ln]      = f2b(acc[mt][0][i]);
                H2[(size_t)m * NCLS + 16 + ln] = f2b(acc[mt][1][i]);
                if (ln < 8)
                    H2[(size_t)m * NCLS + 32 + ln] = f2b(acc[mt][2][i]);
            }
        }
    }
}

// ---------------- SpMM2: out = A_hat @ H2 + b2, F=40 compact ----------------
// 2 rows/wave, lanes fl<20 active; 8-deep gather unroll.

__global__ __launch_bounds__(256) void spmm2_kernel(const int* __restrict__ row_ptr,
                                                    const int2* __restrict__ cv,
                                                    const ushort_t* __restrict__ H2,
                                                    const float* __restrict__ b2,
                                                    float* __restrict__ out, int N) {
    int wave = threadIdx.x >> 6, lane = threadIdx.x & 63;
    int half = lane >> 5, fl = lane & 31;
    int r = blockIdx.x * 8 + wave * 2 + half;
    if (r >= N || fl >= NCLS / 2) return;
    int s = row_ptr[r], e = row_ptr[r + 1];
    float a0 = 0.f, a1 = 0.f;
    int j = s;
    for (; j + 7 < e; j += 8) {
        int2 p[8];
        uint_t h[8];
#pragma unroll
        for (int q = 0; q < 8; q++) p[q] = cv[j + q];
#pragma unroll
        for (int q = 0; q < 8; q++)
            h[q] = *(const uint_t*)(H2 + (size_t)p[q].x * NCLS + fl * 2);
#pragma unroll
        for (int q = 0; q < 8; q++) {
            float v = __int_as_float(p[q].y);
            a0 += v * b2f((ushort_t)(h[q] & 0xffff));
            a1 += v * b2f((ushort_t)(h[q] >> 16));
        }
    }
    for (; j < e; j++) {
        int2 p = cv[j];
        float v = __int_as_float(p.y);
        uint_t h = *(const uint_t*)(H2 + (size_t)p.x * NCLS + fl * 2);
        a0 += v * b2f((ushort_t)(h & 0xffff));
        a1 += v * b2f((ushort_t)(h >> 16));
    }
    float2 o;
    o.x = a0 + b2[fl * 2];
    o.y = a1 + b2[fl * 2 + 1];
    *(float2*)(out + (size_t)r * NCLS + fl * 2) = o;
}

// ---------------- launch ----------------

static inline size_t align256(size_t x) { return (x + 255) & ~(size_t)255; }

extern "C" void kernel_launch(void* const* d_in, const int* in_sizes, int n_in,
                              void* d_out, int out_size, void* d_ws, size_t ws_size,
                              hipStream_t stream) {
    const float* x        = (const float*)d_in[0];
    const float* W1       = (const float*)d_in[1];
    const float* b1       = (const float*)d_in[2];
    const float* W2       = (const float*)d_in[3];
    const float* b2       = (const float*)d_in[4];
    const int*   edge_row = (const int*)d_in[5];
    const int*   edge_col = (const int*)d_in[6];
    const float* edge_val = (const float*)d_in[7];
    float* out = (float*)d_out;

    int N = in_sizes[0] / NFEATS;  // 100000
    int E = in_sizes[5];           // 1700000

    char* w = (char*)d_ws;
    size_t off = 0;
    ushort_t* H1   = (ushort_t*)(w + off); off += align256((size_t)N * NHIDS * 2);
    ushort_t* AGG  = (ushort_t*)(w + off); off += align256((size_t)N * NHIDS * 2);
    ushort_t* H2   = (ushort_t*)(w + off); off += align256((size_t)N * NCLS * 2);
    ushort_t* W1f  = (ushort_t*)(w + off); off += align256((size_t)NHIDS * NFEATS * 2);
    ushort_t* W2f  = (ushort_t*)(w + off); off += align256((size_t)64 * NHIDS * 2);
    int*      row_ptr = (int*)(w + off); off += align256((size_t)(N + 1) * 4);
    int*      cnt     = (int*)(w + off); off += align256((size_t)N * 4);
    int*      blockSums = (int*)(w + off); off += align256((size_t)SS_T * 4);
    int2*     cv      = (int2*)(w + off); off += align256((size_t)E * 8);

    int scanB = (N + PS_CHUNK - 1) / PS_CHUNK;   // 98 for N=100000 (must be <= SS_T)

    // CSR build + weight conversion
    hipMemsetAsync(cnt, 0, (size_t)N * 4, stream);
    hist_kernel<<<(E + 255) / 256, 256, 0, stream>>>(edge_row, cnt, E);
    convert_w1<<<(NFEATS * NHIDS) / 256, 256, 0, stream>>>(W1, W1f);
    convert_w2<<<(64 * NHIDS) / 256, 256, 0, stream>>>(W2, W2f);
    scan_partial_kernel<<<scanB, PS_T, 0, stream>>>(cnt, blockSums, N);
    scan_sums_kernel<<<1, SS_T, 0, stream>>>(blockSums, scanB);
    scan_finalize_kernel<<<scanB, PS_T, 0, stream>>>(cnt, blockSums, row_ptr, N, E);
    scatter_kernel<<<(E + 255) / 256, 256, 0, stream>>>(edge_row, edge_col, edge_val,
                                                        row_ptr, cnt, cv, E);

    // layer 1
    gemm1_kernel<<<(N + G1_BM - 1) / G1_BM, 256, 0, stream>>>(x, W1f, H1, N);
    spmm1_kernel<<<(N + 3) / 4, 256, 0, stream>>>(row_ptr, cv, H1, b1, AGG, N);

    // layer 2
    gemm2_kernel<<<(N + 255) / 256, 256, 0, stream>>>(AGG, W2f, H2, N);
    spmm2_kernel<<<(N + 7) / 8, 256, 0, stream>>>(row_ptr, cv, H2, b2, out, N);
}